// Round 16
// baseline (329.939 us; speedup 1.0000x reference)
//
#include <hip/hip_runtime.h>
#include <hip/hip_bf16.h>

// XLNet rel-attn layer + FFN. Round 16: attention with register double-buffer
// prefetch (tile t+1's kf/vf/kr loads issued before tile t's compute),
// defer-max rescale skip, heavy-first block order. Rest = round 15.
// QLEN=1024 MLEN=1024 BSZ=2 DM=1024 NH=16 DH=64 DI=4096 KLEN=2048 RLEN=3072.

#define QLEN 1024
#define MLEN 1024
#define DM 1024
#define NH 16
#define DH 64
#define DI 4096
#define KLEN 2048
#define RLEN 3072

typedef __attribute__((ext_vector_type(8))) short s16x8;
typedef __attribute__((ext_vector_type(4))) float f32x4;
typedef unsigned short us;

__device__ __forceinline__ float bf2f(us u) {
    union { unsigned int i; float f; } x; x.i = ((unsigned int)u) << 16; return x.f;
}
__device__ __forceinline__ us f2bf(float f) {
    union { float f; unsigned int i; } x; x.f = f;
    return (us)((x.i + 0x7fffu + ((x.i >> 16) & 1u)) >> 16);
}
__device__ __forceinline__ void gload16(const void* g, void* lds) {
    __builtin_amdgcn_global_load_lds(
        (const __attribute__((address_space(1))) unsigned int*)g,
        (__attribute__((address_space(3))) unsigned int*)lds, 16, 0, 0);
}

// ---------------- block reduction (wave=64, 4 waves/block) ------------------
template<bool ISMAX>
__device__ __forceinline__ float block_reduce(float v, float* red, int t) {
    #pragma unroll
    for (int off = 32; off > 0; off >>= 1) {
        float o = __shfl_down(v, off);
        v = ISMAX ? fmaxf(v, o) : (v + o);
    }
    if ((t & 63) == 0) red[t >> 6] = v;
    __syncthreads();
    if (t == 0) {
        float s = red[0];
        #pragma unroll
        for (int w = 1; w < 4; ++w) s = ISMAX ? fmaxf(s, red[w]) : (s + red[w]);
        red[4] = s;
    }
    __syncthreads();
    return red[4];
}

// ---------------- unified prep: converts + transposes + ks extraction -------
__global__ __launch_bounds__(256) void prep_k(
    const float* __restrict__ mems, const float* __restrict__ h,
    const float* __restrict__ r, const float* __restrict__ wo,
    const float* __restrict__ wq, const float* __restrict__ wk,
    const float* __restrict__ wv, const float* __restrict__ wr,
    const float* __restrict__ w1, const float* __restrict__ w2,
    const float* __restrict__ seg,
    us* __restrict__ cat_bf, us* __restrict__ r_bf, us* __restrict__ wo_b,
    us* __restrict__ wqkv_t, us* __restrict__ wr_t,
    us* __restrict__ w1_t, us* __restrict__ w2_t, us* __restrict__ ksb)
{
    __shared__ us tbuf[64][65];
    int bid = blockIdx.x;
    const int tid = threadIdx.x;
    if (bid < 5632) {
        int t = bid * 256 + tid;
        const float* src; us* dst; int off;
        if (t < 262144)       { src = mems; dst = cat_bf;           off = t; }
        else if (t < 524288)  { src = h;    dst = cat_bf + 2097152; off = t - 262144; }
        else if (t < 1310720) { src = r;    dst = r_bf;             off = t - 524288; }
        else                  { src = wo;   dst = wo_b;             off = t - 1310720; }
        const float4* p = (const float4*)src + 2 * (size_t)off;
        float4 a = p[0], b = p[1];
        us o[8] = { f2bf(a.x), f2bf(a.y), f2bf(a.z), f2bf(a.w),
                    f2bf(b.x), f2bf(b.y), f2bf(b.z), f2bf(b.w) };
        *((uint4*)dst + off) = *(const uint4*)o;
        return;
    }
    bid -= 5632;
    if (bid >= 3072) {               // ks: ks[b][j] = seg_mat[0,j,b,1]
        int t = (bid - 3072) * 256 + tid;
        int bb = t >> 11, j = t & 2047;
        ksb[t] = f2bf(seg[(size_t)j * 4 + bb * 2 + 1]);
        return;
    }
    const float* in; us* out; int R, C, c0, r0;
    if (bid < 1024) {
        int z = bid >> 8, u = bid & 255;
        in  = (z == 0) ? wq : (z == 1) ? wk : (z == 2) ? wv : wr;
        out = (z < 3) ? (wqkv_t + (size_t)z * 1048576) : wr_t;
        R = 1024; C = 1024; c0 = (u & 15) * 64; r0 = (u >> 4) * 64;
    } else if (bid < 2048) {
        int u = bid - 1024;
        in = w1; out = w1_t; R = 1024; C = 4096;
        c0 = (u & 63) * 64; r0 = (u >> 6) * 64;
    } else {
        int u = bid - 2048;
        in = w2; out = w2_t; R = 4096; C = 1024;
        c0 = (u & 15) * 64; r0 = (u >> 4) * 64;
    }
    #pragma unroll
    for (int u = 0; u < 16; ++u) {
        int idx = tid + 256 * u;
        int rr = idx >> 6, cc = idx & 63;
        tbuf[cc][rr] = f2bf(in[(size_t)(r0 + rr) * C + c0 + cc]);
    }
    __syncthreads();
    #pragma unroll
    for (int u = 0; u < 16; ++u) {
        int idx = tid + 256 * u;
        int rr = idx >> 6, cc = idx & 63;
        out[(size_t)(c0 + rr) * R + r0 + cc] = tbuf[rr][cc];
    }
}

// ---------------- 256x256 8-wave BK=64 GEMM core (swizzled LDS) -------------
__device__ __forceinline__ int offe(int r, int c) {
    return ((r >> 4) * 2 + (c >> 5)) * 512 + (r & 15) * 32 + ((c & 31) ^ ((r & 8) ? 16 : 0));
}

// EPI 3: kr fragment-major scatter; EPI 4: merged qkv scatter.
template<int EPI>
__device__ __forceinline__ void gemm8_core(
    const us* __restrict__ A, const us* __restrict__ Bt,
    const float* __restrict__ bias, void* __restrict__ Cout,
    int N, int K, int kbeg, size_t zoff, bool zfirst,
    int bx, int by, us* __restrict__ As8, us* __restrict__ Bs8)
{
    const int tid = threadIdx.x;
    const int w = tid >> 6, l = tid & 63;
    const int lm = l & 15, lg = l >> 4;
    const int wm = w >> 2, wn = w & 3;
    const int m0 = by * 256, n0 = bx * 256;

    int srow[2], scol[2];
    #pragma unroll
    for (int u = 0; u < 2; ++u) {
        int sub = w * 2 + u;
        srow[u] = (sub >> 1) * 16 + (l >> 2);
        scol[u] = (sub & 1) * 32 + (((l & 3) * 8) ^ ((l & 32) ? 16 : 0));
    }

    auto stagePart = [&](int kt1, int P, int db) {
        const us* src = (P < 2) ? (A + (size_t)(m0 + P * 128) * K)
                                : (Bt + (size_t)(n0 + (P - 2) * 128) * K);
        us* dst = ((P < 2) ? As8 : Bs8) + (db * 2 + (P & 1)) * 8192;
        int kc = kbeg + kt1 * 64;
        #pragma unroll
        for (int u = 0; u < 2; ++u)
            gload16(src + (size_t)srow[u] * K + kc + scol[u], dst + (w * 2 + u) * 512);
    };

    f32x4 acc[8][4] = {};
    s16x8 rA0[4][2], rA1[4][2], rB[2][2];

    stagePart(0, 0, 0); stagePart(0, 1, 0); stagePart(0, 2, 0); stagePart(0, 3, 0);

    for (int kt = 0; kt < 16; ++kt) {
        const int d = kt & 1;
        asm volatile("s_waitcnt vmcnt(0)" ::: "memory");
        __builtin_amdgcn_s_barrier();
        asm volatile("" ::: "memory");
        const bool hn = (kt + 1 < 16);
        const us* Ab = As8 + (d * 2 + wm) * 8192;
        const us* Bb = Bs8 + (d * 2 + (wn >> 1)) * 8192;

        if (hn) stagePart(kt + 1, 0, d ^ 1);
        #pragma unroll
        for (int mf2 = 0; mf2 < 4; ++mf2)
            #pragma unroll
            for (int kk = 0; kk < 2; ++kk)
                rA0[mf2][kk] = *(const s16x8*)&Ab[offe(mf2 * 16 + lm, kk * 32 + lg * 8)];
        #pragma unroll
        for (int nf2 = 0; nf2 < 2; ++nf2)
            #pragma unroll
            for (int kk = 0; kk < 2; ++kk)
                rB[nf2][kk] = *(const s16x8*)&Bb[offe((wn & 1) * 64 + nf2 * 16 + lm, kk * 32 + lg * 8)];
        __builtin_amdgcn_s_setprio(1);
        #pragma unroll
        for (int mf2 = 0; mf2 < 4; ++mf2)
            #pragma unroll
            for (int nf2 = 0; nf2 < 2; ++nf2)
                #pragma unroll
                for (int kk = 0; kk < 2; ++kk)
                    acc[mf2][nf2] = __builtin_amdgcn_mfma_f32_16x16x32_bf16(
                        rA0[mf2][kk], rB[nf2][kk], acc[mf2][nf2], 0, 0, 0);
        __builtin_amdgcn_s_setprio(0);

        if (hn) stagePart(kt + 1, 1, d ^ 1);
        #pragma unroll
        for (int mf2 = 0; mf2 < 4; ++mf2)
            #pragma unroll
            for (int kk = 0; kk < 2; ++kk)
                rA1[mf2][kk] = *(const s16x8*)&Ab[offe(64 + mf2 * 16 + lm, kk * 32 + lg * 8)];
        __builtin_amdgcn_s_setprio(1);
        #pragma unroll
        for (int mf2 = 0; mf2 < 4; ++mf2)
            #pragma unroll
            for (int nf2 = 0; nf2 < 2; ++nf2)
                #pragma unroll
                for (int kk = 0; kk < 2; ++kk)
                    acc[4 + mf2][nf2] = __builtin_amdgcn_mfma_f32_16x16x32_bf16(
                        rA1[mf2][kk], rB[nf2][kk], acc[4 + mf2][nf2], 0, 0, 0);
        __builtin_amdgcn_s_setprio(0);

        if (hn) stagePart(kt + 1, 2, d ^ 1);
        #pragma unroll
        for (int nf2 = 0; nf2 < 2; ++nf2)
            #pragma unroll
            for (int kk = 0; kk < 2; ++kk)
                rB[nf2][kk] = *(const s16x8*)&Bb[offe((wn & 1) * 64 + (2 + nf2) * 16 + lm, kk * 32 + lg * 8)];
        __builtin_amdgcn_s_setprio(1);
        #pragma unroll
        for (int mf2 = 0; mf2 < 4; ++mf2)
            #pragma unroll
            for (int nf2 = 0; nf2 < 2; ++nf2)
                #pragma unroll
                for (int kk = 0; kk < 2; ++kk)
                    acc[4 + mf2][2 + nf2] = __builtin_amdgcn_mfma_f32_16x16x32_bf16(
                        rA1[mf2][kk], rB[nf2][kk], acc[4 + mf2][2 + nf2], 0, 0, 0);
        __builtin_amdgcn_s_setprio(0);

        if (hn) stagePart(kt + 1, 3, d ^ 1);
        __builtin_amdgcn_s_setprio(1);
        #pragma unroll
        for (int mf2 = 0; mf2 < 4; ++mf2)
            #pragma unroll
            for (int nf2 = 0; nf2 < 2; ++nf2)
                #pragma unroll
                for (int kk = 0; kk < 2; ++kk)
                    acc[mf2][2 + nf2] = __builtin_amdgcn_mfma_f32_16x16x32_bf16(
                        rA0[mf2][kk], rB[nf2][kk], acc[mf2][2 + nf2], 0, 0, 0);
        __builtin_amdgcn_s_setprio(0);
    }

    #pragma unroll
    for (int mf = 0; mf < 8; ++mf) {
        #pragma unroll
        for (int nf = 0; nf < 4; ++nf) {
            #pragma unroll
            for (int rr = 0; rr < 4; ++rr) {
                int row = m0 + wm * 128 + mf * 16 + lg * 4 + rr;
                int col = n0 + wn * 64 + nf * 16 + lm;
                float v = acc[mf][nf][rr];
                if (EPI == 3) {
                    int s = row >> 1, bb = row & 1, nn = col >> 6, dd = col & 63;
                    if (s >= 1) {
                        int g = (s - 1) >> 4, lmw = (s - 1) & 15;
                        int ks2 = dd >> 5, lg2 = (dd >> 3) & 3, e2 = dd & 7;
                        ((us*)Cout)[((((size_t)(bb * 16 + nn)) * 144 + g) * 2 + ks2) * 512
                                    + (lg2 * 16 + lmw) * 8 + e2] = f2bf(v);
                    }
                } else {  // EPI 4
                    int which = col >> 10;
                    int nn = (col >> 6) & 15, dd = col & 63, bb = row & 1;
                    us val = f2bf(v);
                    us* base = (us*)Cout;
                    if (which == 0) {
                        if (row >= 2048)
                            base[(((size_t)(bb * 16 + nn)) * 1024 + ((row - 2048) >> 1)) * 64 + dd] = val;
                    } else if (which == 1) {
                        int j = row >> 1;
                        int jt = j >> 6, ff = (j >> 4) & 3, lmw = j & 15;
                        int ks2 = dd >> 5, lg2 = (dd >> 3) & 3, e2 = dd & 7;
                        (base + 2097152)[((((size_t)(bb * 16 + nn)) * 32 + jt) * 8 + ff * 2 + ks2) * 512
                                         + (lg2 * 16 + lmw) * 8 + e2] = val;
                    } else {
                        int j = row >> 1;
                        int jt = j >> 6, ks2 = (j >> 5) & 1, lg2 = (j >> 3) & 3, e2 = j & 7;
                        int df = dd >> 4, lmw = dd & 15;
                        (base + 6291456)[((((size_t)(bb * 16 + nn)) * 32 + jt) * 8 + df * 2 + ks2) * 512
                                         + (lg2 * 16 + lmw) * 8 + e2] = val;
                    }
                }
            }
        }
    }
}

// ---------------- merged projections: qkv (192 blocks) + kr (72 blocks) -----
__global__ __launch_bounds__(512) void proj8_k(
    const us* __restrict__ cat_bf, const us* __restrict__ wqkv_t,
    const us* __restrict__ r_bf, const us* __restrict__ wr_t,
    us* __restrict__ qkv_out, us* __restrict__ krf_out)
{
    __shared__ __align__(16) us As8[2 * 2 * 8192];
    __shared__ __align__(16) us Bs8[2 * 2 * 8192];
    int bid = blockIdx.x;
    if (bid < 192) {
        int swz = (bid & 7) * 24 + (bid >> 3);
        gemm8_core<4>(cat_bf, wqkv_t, nullptr, qkv_out, 3072, 1024, 0,
                      0, true, swz % 12, swz / 12, As8, Bs8);
    } else {
        int idx = bid - 192;
        gemm8_core<3>(r_bf, wr_t, nullptr, krf_out, 1024, 1024, 0,
                      0, true, idx & 3, idx >> 2, As8, Bs8);
    }
}

// ---------------- 4-wave 2-phase GEMM core (wo / ff1 / ff2) -----------------
template<int TM, int EPI>
__device__ __forceinline__ void gemm_core(
    const us* __restrict__ A, const us* __restrict__ Bt,
    const float* __restrict__ bias, void* __restrict__ Cout,
    int N, int K, int kbeg, int kchunk, size_t zoff, bool zfirst,
    int bx, int by, us* __restrict__ As, us* __restrict__ Bs)
{
    constexpr int MF = TM / 32;
    constexpr int AISS = TM / 64;
    const int tid = threadIdx.x;
    const int w = tid >> 6, l = tid & 63;
    const int lm = l & 15, lg = l >> 4;
    const int m0 = by * TM, n0 = bx * 128;
    const int wr = (w >> 1) * (TM / 2), wc = (w & 1) * 64;
    const int nt = kchunk / 32;

    f32x4 acc[MF][4] = {};

    auto stage = [&](int buf, int k0) {
        #pragma unroll
        for (int u = 0; u < AISS; ++u) {
            int c = (u * 4 + w) * 64 + l;
            int row = c & (TM - 1), kc = c >> (TM == 128 ? 7 : 6);
            gload16(A + (size_t)(m0 + row) * K + k0 + kc * 8,
                    As + buf * (TM * 32) + (u * 4 + w) * 512);
        }
        #pragma unroll
        for (int u = 0; u < 2; ++u) {
            int c = (u * 4 + w) * 64 + l;
            int row = c & 127, kc = c >> 7;
            gload16(Bt + (size_t)(n0 + row) * K + k0 + kc * 8,
                    Bs + buf * 4096 + (u * 4 + w) * 512);
        }
    };

    stage(0, kbeg);
    int cur = 0;
    for (int t = 0; t < nt; ++t) {
        asm volatile("s_waitcnt vmcnt(0)" ::: "memory");
        __builtin_amdgcn_s_barrier();
        asm volatile("" ::: "memory");
        if (t + 1 < nt) stage(cur ^ 1, kbeg + (t + 1) * 32);

        s16x8 af[MF], bfr[4];
        #pragma unroll
        for (int mf = 0; mf < MF; ++mf)
            af[mf] = *(const s16x8*)&As[cur * (TM * 32) + (lg * TM + wr + mf * 16 + lm) * 8];
        #pragma unroll
        for (int nf = 0; nf < 4; ++nf)
            bfr[nf] = *(const s16x8*)&Bs[cur * 4096 + (lg * 128 + wc + nf * 16 + lm) * 8];
        #pragma unroll
        for (int mf = 0; mf < MF; ++mf)
            #pragma unroll
            for (int nf = 0; nf < 4; ++nf)
                acc[mf][nf] = __builtin_amdgcn_mfma_f32_16x16x32_bf16(
                    af[mf], bfr[nf], acc[mf][nf], 0, 0, 0);
        cur ^= 1;
    }

    #pragma unroll
    for (int mf = 0; mf < MF; ++mf) {
        #pragma unroll
        for (int nf = 0; nf < 4; ++nf) {
            #pragma unroll
            for (int rr = 0; rr < 4; ++rr) {
                int row = m0 + wr + mf * 16 + lg * 4 + rr;
                int col = n0 + wc + nf * 16 + lm;
                float v = acc[mf][nf][rr];
                if (EPI == 1 || (EPI == 2 && zfirst)) v += bias[col];
                if (EPI == 1) {
                    float targ = 0.7978845608028654f * (v + 0.044715f * v * v * v);
                    v = 0.5f * v * (1.0f + tanhf(targ));
                    ((us*)Cout)[(size_t)row * N + col] = f2bf(v);
                } else {
                    ((float*)Cout + zoff)[(size_t)row * N + col] = v;
                }
            }
        }
    }
}

template<int TM, int EPI>
__global__ __launch_bounds__(256) void gemm2(
    const us* __restrict__ A, const us* __restrict__ Bt,
    const float* __restrict__ bias, void* __restrict__ Cout,
    int N, int K, int kchunk, size_t zstride)
{
    __shared__ us As[2 * TM * 32];
    __shared__ us Bs[2 * 128 * 32];
    int lin = blockIdx.y * gridDim.x + blockIdx.x;
    int nwg = gridDim.x * gridDim.y;
    int swz = (lin & 7) * (nwg >> 3) + (lin >> 3);
    int bx = swz % gridDim.x, by = swz / gridDim.x;
    gemm_core<TM, EPI>(A, Bt, bias, Cout, N, K, blockIdx.z * kchunk, kchunk,
                       (size_t)blockIdx.z * zstride, blockIdx.z == 0, bx, by, As, Bs);
}

// ---------------- barrier-free attention + register prefetch + defer-max ----
__global__ __launch_bounds__(256) void attn10_k(
    const us* __restrict__ qb, const us* __restrict__ kfr, const us* __restrict__ vfr,
    const us* __restrict__ krf, const us* __restrict__ ksb,
    const float* __restrict__ rwb, const float* __restrict__ rrb,
    const float* __restrict__ rsb, const float* __restrict__ se,
    const float* __restrict__ seg,
    us* __restrict__ av)
{
    __shared__ float G_lds[4 * 80 * 20];
    __shared__ us P_lds[4 * 16 * 64];
    __shared__ us KS_lds[2048];
    __shared__ float Qx_lds[64][2];

    const int tid = threadIdx.x;
    const int w = tid >> 6, l = tid & 63;
    const int lm = l & 15, lg = l >> 4;
    int lin = blockIdx.x;                       // 512 blocks, heavy-first
    const int i0t = 15 - (lin >> 5);
    const int bn = lin & 31;
    const int i0 = i0t * 64;
    const int b = bn >> 4, n = bn & 15;
    const int i = i0 + w * 16 + lm;

    const float SC = 0.125f * 1.44269504088896340736f;
    const float THR = 11.5416f;                 // 8 * log2(e), defer-max bound

    const us* kbase = kfr + (size_t)bn * 131072;
    const us* vbase = vfr + (size_t)bn * 131072;
    const us* krbase = krf + (size_t)bn * 147456;

    gload16(ksb + b * KLEN + (w * 64 + l) * 8, &KS_lds[w * 512]);
    {
        const us* qrow = qb + ((size_t)bn * QLEN + i0 + l) * DH;
        s16x8 qv8[8];
        #pragma unroll
        for (int c = 0; c < 8; ++c) qv8[c] = *(const s16x8*)(qrow + c * 8);
        float e0 = 0.f, e1 = 0.f;
        #pragma unroll
        for (int c = 0; c < 8; ++c)
            #pragma unroll
            for (int e = 0; e < 8; ++e) {
                int d = c * 8 + e;
                float qv = bf2f((us)qv8[c][e]) + rsb[n * DH + d];
                e0 = fmaf(qv, se[(0 * NH + n) * DH + d], e0);
                e1 = fmaf(qv, se[(1 * NH + n) * DH + d], e1);
            }
        float qsI = seg[(size_t)(i0 + l) * 8192 + b * 2 + 1];
        float qs0 = seg[b * 2 + 1];
        float qs = (qsI != qs0) ? 1.f : 0.f;
        float ed = e1 - e0;
        if (w == 0) {
            Qx_lds[l][0] = (e0 + qs * ed) * SC;
            Qx_lds[l][1] = ed * (1.f - 2.f * qs) * SC;
        }
    }
    asm volatile("s_waitcnt vmcnt(0)" ::: "memory");
    __syncthreads();

    s16x8 qwf[2], qrf[2], qxf;
    {
        const us* qrow = qb + ((size_t)bn * QLEN + i) * DH;
        #pragma unroll
        for (int ks = 0; ks < 2; ++ks) {
            s16x8 v = *(const s16x8*)(qrow + ks * 32 + lg * 8);
            #pragma unroll
            for (int e = 0; e < 8; ++e) {
                int d = ks * 32 + lg * 8 + e;
                float f = bf2f((us)v[e]);
                qwf[ks][e] = (short)f2bf((f + rwb[n * DH + d]) * SC);
                qrf[ks][e] = (short)f2bf((f + rrb[n * DH + d]) * SC);
            }
        }
        #pragma unroll
        for (int e = 0; e < 8; ++e) qxf[e] = 0;
        if (lg == 0) {
            qxf[0] = (short)f2bf(Qx_lds[w * 16 + lm][0]);
            qxf[1] = (short)f2bf(Qx_lds[w * 16 + lm][1]);
        }
    }

    int njt = ((i0 + 63 + MLEN) >> 6) + 1;
    if (njt > 32) njt = 32;
    const int gq = 63 - (i0 >> 4) - w;

    f32x4 of[4] = {{0,0,0,0},{0,0,0,0},{0,0,0,0},{0,0,0,0}};
    float M = -3.0e38f, L = 0.f;
    float* gw = &G_lds[w * 1600];
    us* pw = &P_lds[w * 1024];

    auto loadT = [&](s16x8 (&kf)[4][2], s16x8 (&vf)[4][2], s16x8 (&kr)[5][2], int jt) {
        #pragma unroll
        for (int f = 0; f < 4; ++f)
            #pragma unroll
            for (int ks = 0; ks < 2; ++ks) {
                kf[f][ks] = *(const s16x8*)(kbase + (size_t)(((jt * 4 + f) * 2 + ks) * 64 + l) * 8);
                vf[f][ks] = *(const s16x8*)(vbase + (size_t)(((jt * 4 + f) * 2 + ks) * 64 + l) * 8);
            }
        #pragma unroll
        for (int pf = 0; pf < 5; ++pf) {
            int g = gq + 4 * jt + pf;
            #pragma unroll
            for (int ks = 0; ks < 2; ++ks)
                kr[pf][ks] = *(const s16x8*)(krbase + (size_t)((g * 2 + ks) * 64 + l) * 8);
        }
    };

    auto computeT = [&](s16x8 (&kf)[4][2], s16x8 (&vf)[4][2], s16x8 (&kr)[5][2], int j0) {
        __builtin_amdgcn_s_setprio(1);
        #pragma unroll
        for (int pf = 0; pf < 5; ++pf) {
            f32x4 gacc = {0, 0, 0, 0};
            gacc = __builtin_amdgcn_mfma_f32_16x16x32_bf16(kr[pf][0], qrf[0], gacc, 0, 0, 0);
            gacc = __builtin_amdgcn_mfma_f32_16x16x32_bf16(kr[pf][1], qrf[1], gacc, 0, 0, 0);
            #pragma unroll
            for (int rr = 0; rr < 4; ++rr)
                gw[(pf * 16 + lg * 4 + rr) * 20 + lm] = gacc[rr];
        }
        f32x4 sf[4];
        #pragma unroll
        for (int f = 0; f < 4; ++f) {
            f32x4 cfr = {0, 0, 0, 0};
            cfr = __builtin_amdgcn_mfma_f32_16x16x32_bf16(kf[f][0], qwf[0], cfr, 0, 0, 0);
            cfr = __builtin_amdgcn_mfma_f32_16x16x32_bf16(kf[f][1], qwf[1], cfr, 0, 0, 0);
            s16x8 aext;
            #pragma unroll
            for (int e = 0; e < 8; ++e) aext[e] = 0;
            if (lg == 0) {
                aext[0] = (short)0x3F80;
                aext[1] = (short)KS_lds[j0 + f * 16 + lm];
            }
            cfr = __builtin_amdgcn_mfma_f32_16x16x32_bf16(aext, qxf, cfr, 0, 0, 0);
            sf[f] = cfr;
        }
        __builtin_amdgcn_s_setprio(0);

        float sv[16];
        #pragma unroll
        for (int f = 0; f < 4; ++f)
            #pragma unroll
            for (int rr = 0; rr < 4; ++rr) {
                int jl = f * 16 + lg * 4 + rr;
                sv[f * 4 + rr] = sf[f][rr] + gw[(jl + 15 - lm) * 20 + lm];
            }
        if (j0 + 63 > i0 + w * 16 + MLEN) {
            #pragma unroll
            for (int f = 0; f < 4; ++f)
                #pragma unroll
                for (int rr = 0; rr < 4; ++rr) {
                    int jl = f * 16 + lg * 4 + rr;
                    if (j0 + jl > i + MLEN) sv[f * 4 + rr] = -1.0e30f;
                }
        }
        float tmax = sv[0];
        #pragma unroll
        for (int u = 1; u < 16; ++u) tmax = fmaxf(tmax, sv[u]);
        tmax = fmaxf(tmax, __shfl_xor(tmax, 16));
        tmax = fmaxf(tmax, __shfl_xor(tmax, 32));

        // defer-max: keep stale M while growth <= THR (exp2 domain)
        const bool defer = __all(tmax - M <= THR);
        float Mnew = defer ? M : fmaxf(M, tmax);
        float psum = 0.f;
        unsigned int pk[8];
        #pragma unroll
        for (int f = 0; f < 4; ++f) {
            #pragma unroll
            for (int rp = 0; rp < 2; ++rp) {
                float p0, p1;
                asm("v_exp_f32 %0, %1" : "=v"(p0) : "v"(sv[f * 4 + rp * 2] - Mnew));
                asm("v_exp_f32 %0, %1" : "=v"(p1) : "v"(sv[f * 4 + rp * 2 + 1] - Mnew));
                psum += p0 + p1;
                unsigned int pkv;
                asm("v_cvt_pk_bf16_f32 %0, %1, %2" : "=v"(pkv) : "v"(p0), "v"(p1));
                pk[f * 2 + rp] = pkv;
            }
        }
        psum += __shfl_xor(psum, 16);
        psum += __shfl_xor(psum, 32);
        if (defer) {
            L += psum;
        } else {
            float scale;
            asm("v_exp_f32 %0, %1" : "=v"(scale) : "v"(M - Mnew));
            L = L * scale + psum;
            M = Mnew;
            float rs4[4];
            #pragma unroll
            for (int rr = 0; rr < 4; ++rr)
                rs4[rr] = __shfl(scale, (l & 48) | (lg * 4 + rr));
            #pragma unroll
            for (int df = 0; df < 4; ++df)
                #pragma unroll
                for (int rr = 0; rr < 4; ++rr)
                    of[df][rr] *= rs4[rr];
        }
        #pragma unroll
        for (int f = 0; f < 4; ++f) {
            #pragma unroll
            for (int rp = 0; rp < 2; ++rp) {
                int jl2 = f * 16 + lg * 4 + rp * 2;
                *(unsigned int*)&pw[lm * 64 + (((jl2 * 2) ^ ((lm & 7) << 4)) >> 1)] = pk[f * 2 + rp];
            }
        }
        __builtin_amdgcn_s_setprio(1);
        #pragma unroll
        for (int ks = 0; ks < 2; ++ks) {
            s16x8 pa = *(const s16x8*)&pw[lm * 64 + (((ks * 64 + lg * 16) ^ ((lm & 7) << 4)) >> 1)];
            #pragma unroll
            for (int df = 0; df < 4; ++df)
                of[df] = __builtin_amdgcn_mfma_f32_16x16x32_bf16(pa, vf[df][ks], of[df], 0, 0, 0);
        }
        __builtin_amdgcn_s_setprio(0);
    };

    // register double-buffer: prefetch tile t+1 before computing tile t
    s16x8 kfA[4][2], vfA[4][2], krA[5][2];
    s16x8 kfB[4][2], vfB[4][2], krB[5][2];
    loadT(kfA, vfA, krA, 0);
    for (int jt = 0; jt < njt; ++jt) {
        const bool hn = (jt + 1 < njt);
        if ((jt & 1) == 0) {
            if (hn) loadT(kfB, vfB, krB, jt + 1);
            computeT(kfA, vfA, krA, jt * 64);
        } else {
            if (hn) loadT(kfA, vfA, krA, jt + 1);
            computeT(kfB, vfB, krB, jt * 64);
        }
    }

    float rl4[4];
    #pragma unroll
    for (int rr = 0; rr < 4; ++rr)
        rl4[rr] = __shfl(L, (l & 48) | (lg * 4 + rr));
    #pragma unroll
    for (int df = 0; df < 4; ++df) {
        #pragma unroll
        for (int rr = 0; rr < 4; ++rr) {
            int m2 = lg * 4 + rr;
            int d = df * 16 + lm;
            int irow = i0 + w * 16 + m2;
            av[((size_t)irow * 2 + b) * DM + n * DH + d] = f2bf(of[df][rr] / rl4[rr]);
        }
    }
}

// ---------------- residual + layer-norm (sums NSUM partials) ----------------
template<int NSUM, bool RESBF, bool OUTBF>
__global__ __launch_bounds__(256) void ln_k(
    const float* __restrict__ a, const void* __restrict__ resid,
    const float* __restrict__ g, const float* __restrict__ bb,
    void* __restrict__ out)
{
    __shared__ float xs[DM];
    __shared__ float red[5];
    const int r = blockIdx.x;
    const int t = threadIdx.x;
    float lsum = 0.f;
    #pragma unroll
    for (int u = 0; u < 4; ++u) {
        int hdx = t + 256 * u;
        float x = RESBF ? bf2f(((const us*)resid)[(size_t)r * DM + hdx])
                        : ((const float*)resid)[(size_t)r * DM + hdx];
        #pragma unroll
        for (int s = 0; s < NSUM; ++s)
            x += a[(size_t)s * 2097152 + (size_t)r * DM + hdx];
        xs[hdx] = x;
        lsum += x;
    }
    float m = block_reduce<false>(lsum, red, t) * (1.0f / DM);
    float lv = 0.f;
    #pragma unroll
    for (int u = 0; u < 4; ++u) {
        int hdx = t + 256 * u;
        float dd = xs[hdx] - m;
        lv += dd * dd;
    }
    float var = block_reduce<false>(lv, red, t) * (1.0f / DM);
    float rs = rsqrtf(var + 1e-12f);
    #pragma unroll
    for (int u = 0; u < 4; ++u) {
        int hdx = t + 256 * u;
        float y = (xs[hdx] - m) * rs * g[hdx] + bb[hdx];
        if (OUTBF) ((us*)out)[(size_t)r * DM + hdx] = f2bf(y);
        else       ((float*)out)[(size_t)r * DM + hdx] = y;
    }
}

// ---------------- launch -----------------------------------------------------
extern "C" void kernel_launch(void* const* d_in, const int* in_sizes, int n_in,
                              void* d_out, int out_size, void* d_ws, size_t ws_size,
                              hipStream_t stream) {
    const float* h         = (const float*)d_in[0];
    const float* mems      = (const float*)d_in[1];
    const float* r         = (const float*)d_in[2];
    const float* seg_mat   = (const float*)d_in[3];
    const float* wq        = (const float*)d_in[5];
    const float* wk        = (const float*)d_in[6];
    const float* wv        = (const float*)d_in[7];
    const float* wo        = (const float*)d_in[8];
    const float* wr        = (const float*)d_in[9];
    const float* rwb       = (const float*)d_in[10];
    const float* rrb       = (const float*)d_in[11];
    const float* rsb       = (const float*)d_in[12];
    const float* seg_embed = (const float*)d_in[13];
    const float* ln_g      = (const float*)d_in[14];
    const float* ln_b      = (const float*)d_in[15];
    const float* w1        = (const float*)d_in[16];
    const float* b1        = (const float*)d_in[17];
    const float* w2        = (const float*)d_in[18];
    const float* b2        = (const float*)d_in[19];
    const float* lf_g      = (const float*)d_in[20];
    const float* lf_b      = (const float*)d_in[21];
    float* out = (float*)d_out;
    char* W = (char*)d_ws;
    const size_t MB = 1ull << 20;

    us*    cat_bf = (us*)(W);                 // [0,8)
    us*    r_bf   = (us*)(W + 8  * MB);       // [8,20)
    us*    wqkv_t = (us*)(W + 20 * MB);       // [20,26)
    us*    wr_t   = (us*)(W + 26 * MB);       // [26,28)
    us*    wo_b   = (us*)(W + 28 * MB);       // [28,30)
    us*    w1_t   = (us*)(W + 30 * MB);       // [30,38)
    us*    w2_t   = (us*)(W + 38 * MB);       // [38,46)
    us*    q_bf   = (us*)(W + 46 * MB);       // [46,50)
    us*    kfrag  = q_bf + 2097152;           // [50,58)
    us*    vfrag  = q_bf + 6291456;           // [58,66)
    us*    krf    = (us*)(W + 66 * MB);       // [66,75.4)
    us*    av_bf  = (us*)(W + 78 * MB);       // [78,82)
    us*    ks_bf  = (us*)(W + 82 * MB);       // 8 KB
    us*    oh_bf  = (us*)(W + 83 * MB);       // [83,87)
    float* ao     = (float*)(W + 8 * MB);     // overlay [8,24): 2 wo partials
    us*    ff1_bf = (us*)(W + 46 * MB);       // overlay [46,62)
    float* ff2    = (float*)(W);              // overlay [0,32): 4 ff2 partials

    dim3 blk(256);
    dim3 blk8(512);
    prep_k<<<dim3(8720), blk, 0, stream>>>(mems, h, r, wo, wq, wk, wv, wr, w1, w2, seg_mat,
                                           cat_bf, r_bf, wo_b, wqkv_t, wr_t, w1_t, w2_t, ks_bf);
    proj8_k<<<dim3(264), blk8, 0, stream>>>(cat_bf, wqkv_t, r_bf, wr_t, q_bf, krf);
    attn10_k<<<dim3(512), blk, 0, stream>>>(q_bf, kfrag, vfrag, krf, ks_bf,
                                            rwb, rrb, rsb, seg_embed, seg_mat, av_bf);
    gemm2<64, 0><<<dim3(8, 32, 2), blk, 0, stream>>>(av_bf, wo_b, nullptr, ao, 1024, 1024, 512, 2097152);
    ln_k<2, false, true><<<dim3(2048), blk, 0, stream>>>(ao, h, ln_g, ln_b, oh_bf);
    gemm2<128, 1><<<dim3(32, 16), blk, 0, stream>>>(oh_bf, w1_t, b1, ff1_bf, 4096, 1024, 1024, 0);
    gemm2<64, 2><<<dim3(8, 32, 4), blk, 0, stream>>>(ff1_bf, w2_t, b2, ff2, 1024, 4096, 1024, 2097152);
    ln_k<4, true, false><<<dim3(2048), blk, 0, stream>>>(ff2, oh_bf, lf_g, lf_b, out);
}

// Round 17
// 307.077 us; speedup vs baseline: 1.0745x; 1.0745x over previous
//
#include <hip/hip_runtime.h>
#include <hip/hip_bf16.h>

// XLNet rel-attn layer + FFN. Round 17: split-KV attention (each (i-tile,bn)
// handled by TWO blocks over half the j-range, unnormalized partials merged
// by a combine kernel) -> 1024 blocks, 2x occupancy. Attention compute body
// reverted to round-15 (100 VGPR). Rest identical to round 15.
// QLEN=1024 MLEN=1024 BSZ=2 DM=1024 NH=16 DH=64 DI=4096 KLEN=2048 RLEN=3072.

#define QLEN 1024
#define MLEN 1024
#define DM 1024
#define NH 16
#define DH 64
#define DI 4096
#define KLEN 2048
#define RLEN 3072

typedef __attribute__((ext_vector_type(8))) short s16x8;
typedef __attribute__((ext_vector_type(4))) float f32x4;
typedef unsigned short us;

__device__ __forceinline__ float bf2f(us u) {
    union { unsigned int i; float f; } x; x.i = ((unsigned int)u) << 16; return x.f;
}
__device__ __forceinline__ us f2bf(float f) {
    union { float f; unsigned int i; } x; x.f = f;
    return (us)((x.i + 0x7fffu + ((x.i >> 16) & 1u)) >> 16);
}
__device__ __forceinline__ void gload16(const void* g, void* lds) {
    __builtin_amdgcn_global_load_lds(
        (const __attribute__((address_space(1))) unsigned int*)g,
        (__attribute__((address_space(3))) unsigned int*)lds, 16, 0, 0);
}

// ---------------- block reduction (wave=64, 4 waves/block) ------------------
template<bool ISMAX>
__device__ __forceinline__ float block_reduce(float v, float* red, int t) {
    #pragma unroll
    for (int off = 32; off > 0; off >>= 1) {
        float o = __shfl_down(v, off);
        v = ISMAX ? fmaxf(v, o) : (v + o);
    }
    if ((t & 63) == 0) red[t >> 6] = v;
    __syncthreads();
    if (t == 0) {
        float s = red[0];
        #pragma unroll
        for (int w = 1; w < 4; ++w) s = ISMAX ? fmaxf(s, red[w]) : (s + red[w]);
        red[4] = s;
    }
    __syncthreads();
    return red[4];
}

// ---------------- unified prep: converts + transposes + ks extraction -------
__global__ __launch_bounds__(256) void prep_k(
    const float* __restrict__ mems, const float* __restrict__ h,
    const float* __restrict__ r, const float* __restrict__ wo,
    const float* __restrict__ wq, const float* __restrict__ wk,
    const float* __restrict__ wv, const float* __restrict__ wr,
    const float* __restrict__ w1, const float* __restrict__ w2,
    const float* __restrict__ seg,
    us* __restrict__ cat_bf, us* __restrict__ r_bf, us* __restrict__ wo_b,
    us* __restrict__ wqkv_t, us* __restrict__ wr_t,
    us* __restrict__ w1_t, us* __restrict__ w2_t, us* __restrict__ ksb)
{
    __shared__ us tbuf[64][65];
    int bid = blockIdx.x;
    const int tid = threadIdx.x;
    if (bid < 5632) {
        int t = bid * 256 + tid;
        const float* src; us* dst; int off;
        if (t < 262144)       { src = mems; dst = cat_bf;           off = t; }
        else if (t < 524288)  { src = h;    dst = cat_bf + 2097152; off = t - 262144; }
        else if (t < 1310720) { src = r;    dst = r_bf;             off = t - 524288; }
        else                  { src = wo;   dst = wo_b;             off = t - 1310720; }
        const float4* p = (const float4*)src + 2 * (size_t)off;
        float4 a = p[0], b = p[1];
        us o[8] = { f2bf(a.x), f2bf(a.y), f2bf(a.z), f2bf(a.w),
                    f2bf(b.x), f2bf(b.y), f2bf(b.z), f2bf(b.w) };
        *((uint4*)dst + off) = *(const uint4*)o;
        return;
    }
    bid -= 5632;
    if (bid >= 3072) {
        int t = (bid - 3072) * 256 + tid;
        int bb = t >> 11, j = t & 2047;
        ksb[t] = f2bf(seg[(size_t)j * 4 + bb * 2 + 1]);
        return;
    }
    const float* in; us* out; int R, C, c0, r0;
    if (bid < 1024) {
        int z = bid >> 8, u = bid & 255;
        in  = (z == 0) ? wq : (z == 1) ? wk : (z == 2) ? wv : wr;
        out = (z < 3) ? (wqkv_t + (size_t)z * 1048576) : wr_t;
        R = 1024; C = 1024; c0 = (u & 15) * 64; r0 = (u >> 4) * 64;
    } else if (bid < 2048) {
        int u = bid - 1024;
        in = w1; out = w1_t; R = 1024; C = 4096;
        c0 = (u & 63) * 64; r0 = (u >> 6) * 64;
    } else {
        int u = bid - 2048;
        in = w2; out = w2_t; R = 4096; C = 1024;
        c0 = (u & 15) * 64; r0 = (u >> 4) * 64;
    }
    #pragma unroll
    for (int u = 0; u < 16; ++u) {
        int idx = tid + 256 * u;
        int rr = idx >> 6, cc = idx & 63;
        tbuf[cc][rr] = f2bf(in[(size_t)(r0 + rr) * C + c0 + cc]);
    }
    __syncthreads();
    #pragma unroll
    for (int u = 0; u < 16; ++u) {
        int idx = tid + 256 * u;
        int rr = idx >> 6, cc = idx & 63;
        out[(size_t)(c0 + rr) * R + r0 + cc] = tbuf[rr][cc];
    }
}

// ---------------- 256x256 8-wave BK=64 GEMM core (swizzled LDS) -------------
__device__ __forceinline__ int offe(int r, int c) {
    return ((r >> 4) * 2 + (c >> 5)) * 512 + (r & 15) * 32 + ((c & 31) ^ ((r & 8) ? 16 : 0));
}

// EPI 3: kr fragment-major scatter; EPI 4: merged qkv scatter.
template<int EPI>
__device__ __forceinline__ void gemm8_core(
    const us* __restrict__ A, const us* __restrict__ Bt,
    const float* __restrict__ bias, void* __restrict__ Cout,
    int N, int K, int kbeg, size_t zoff, bool zfirst,
    int bx, int by, us* __restrict__ As8, us* __restrict__ Bs8)
{
    const int tid = threadIdx.x;
    const int w = tid >> 6, l = tid & 63;
    const int lm = l & 15, lg = l >> 4;
    const int wm = w >> 2, wn = w & 3;
    const int m0 = by * 256, n0 = bx * 256;

    int srow[2], scol[2];
    #pragma unroll
    for (int u = 0; u < 2; ++u) {
        int sub = w * 2 + u;
        srow[u] = (sub >> 1) * 16 + (l >> 2);
        scol[u] = (sub & 1) * 32 + (((l & 3) * 8) ^ ((l & 32) ? 16 : 0));
    }

    auto stagePart = [&](int kt1, int P, int db) {
        const us* src = (P < 2) ? (A + (size_t)(m0 + P * 128) * K)
                                : (Bt + (size_t)(n0 + (P - 2) * 128) * K);
        us* dst = ((P < 2) ? As8 : Bs8) + (db * 2 + (P & 1)) * 8192;
        int kc = kbeg + kt1 * 64;
        #pragma unroll
        for (int u = 0; u < 2; ++u)
            gload16(src + (size_t)srow[u] * K + kc + scol[u], dst + (w * 2 + u) * 512);
    };

    f32x4 acc[8][4] = {};
    s16x8 rA0[4][2], rA1[4][2], rB[2][2];

    stagePart(0, 0, 0); stagePart(0, 1, 0); stagePart(0, 2, 0); stagePart(0, 3, 0);

    for (int kt = 0; kt < 16; ++kt) {
        const int d = kt & 1;
        asm volatile("s_waitcnt vmcnt(0)" ::: "memory");
        __builtin_amdgcn_s_barrier();
        asm volatile("" ::: "memory");
        const bool hn = (kt + 1 < 16);
        const us* Ab = As8 + (d * 2 + wm) * 8192;
        const us* Bb = Bs8 + (d * 2 + (wn >> 1)) * 8192;

        if (hn) stagePart(kt + 1, 0, d ^ 1);
        #pragma unroll
        for (int mf2 = 0; mf2 < 4; ++mf2)
            #pragma unroll
            for (int kk = 0; kk < 2; ++kk)
                rA0[mf2][kk] = *(const s16x8*)&Ab[offe(mf2 * 16 + lm, kk * 32 + lg * 8)];
        #pragma unroll
        for (int nf2 = 0; nf2 < 2; ++nf2)
            #pragma unroll
            for (int kk = 0; kk < 2; ++kk)
                rB[nf2][kk] = *(const s16x8*)&Bb[offe((wn & 1) * 64 + nf2 * 16 + lm, kk * 32 + lg * 8)];
        __builtin_amdgcn_s_setprio(1);
        #pragma unroll
        for (int mf2 = 0; mf2 < 4; ++mf2)
            #pragma unroll
            for (int nf2 = 0; nf2 < 2; ++nf2)
                #pragma unroll
                for (int kk = 0; kk < 2; ++kk)
                    acc[mf2][nf2] = __builtin_amdgcn_mfma_f32_16x16x32_bf16(
                        rA0[mf2][kk], rB[nf2][kk], acc[mf2][nf2], 0, 0, 0);
        __builtin_amdgcn_s_setprio(0);

        if (hn) stagePart(kt + 1, 1, d ^ 1);
        #pragma unroll
        for (int mf2 = 0; mf2 < 4; ++mf2)
            #pragma unroll
            for (int kk = 0; kk < 2; ++kk)
                rA1[mf2][kk] = *(const s16x8*)&Ab[offe(64 + mf2 * 16 + lm, kk * 32 + lg * 8)];
        __builtin_amdgcn_s_setprio(1);
        #pragma unroll
        for (int mf2 = 0; mf2 < 4; ++mf2)
            #pragma unroll
            for (int nf2 = 0; nf2 < 2; ++nf2)
                #pragma unroll
                for (int kk = 0; kk < 2; ++kk)
                    acc[4 + mf2][nf2] = __builtin_amdgcn_mfma_f32_16x16x32_bf16(
                        rA1[mf2][kk], rB[nf2][kk], acc[4 + mf2][nf2], 0, 0, 0);
        __builtin_amdgcn_s_setprio(0);

        if (hn) stagePart(kt + 1, 2, d ^ 1);
        #pragma unroll
        for (int nf2 = 0; nf2 < 2; ++nf2)
            #pragma unroll
            for (int kk = 0; kk < 2; ++kk)
                rB[nf2][kk] = *(const s16x8*)&Bb[offe((wn & 1) * 64 + (2 + nf2) * 16 + lm, kk * 32 + lg * 8)];
        __builtin_amdgcn_s_setprio(1);
        #pragma unroll
        for (int mf2 = 0; mf2 < 4; ++mf2)
            #pragma unroll
            for (int nf2 = 0; nf2 < 2; ++nf2)
                #pragma unroll
                for (int kk = 0; kk < 2; ++kk)
                    acc[4 + mf2][2 + nf2] = __builtin_amdgcn_mfma_f32_16x16x32_bf16(
                        rA1[mf2][kk], rB[nf2][kk], acc[4 + mf2][2 + nf2], 0, 0, 0);
        __builtin_amdgcn_s_setprio(0);

        if (hn) stagePart(kt + 1, 3, d ^ 1);
        __builtin_amdgcn_s_setprio(1);
        #pragma unroll
        for (int mf2 = 0; mf2 < 4; ++mf2)
            #pragma unroll
            for (int nf2 = 0; nf2 < 2; ++nf2)
                #pragma unroll
                for (int kk = 0; kk < 2; ++kk)
                    acc[mf2][2 + nf2] = __builtin_amdgcn_mfma_f32_16x16x32_bf16(
                        rA0[mf2][kk], rB[nf2][kk], acc[mf2][2 + nf2], 0, 0, 0);
        __builtin_amdgcn_s_setprio(0);
    }

    #pragma unroll
    for (int mf = 0; mf < 8; ++mf) {
        #pragma unroll
        for (int nf = 0; nf < 4; ++nf) {
            #pragma unroll
            for (int rr = 0; rr < 4; ++rr) {
                int row = m0 + wm * 128 + mf * 16 + lg * 4 + rr;
                int col = n0 + wn * 64 + nf * 16 + lm;
                float v = acc[mf][nf][rr];
                if (EPI == 3) {
                    int s = row >> 1, bb = row & 1, nn = col >> 6, dd = col & 63;
                    if (s >= 1) {
                        int g = (s - 1) >> 4, lmw = (s - 1) & 15;
                        int ks2 = dd >> 5, lg2 = (dd >> 3) & 3, e2 = dd & 7;
                        ((us*)Cout)[((((size_t)(bb * 16 + nn)) * 144 + g) * 2 + ks2) * 512
                                    + (lg2 * 16 + lmw) * 8 + e2] = f2bf(v);
                    }
                } else {  // EPI 4
                    int which = col >> 10;
                    int nn = (col >> 6) & 15, dd = col & 63, bb = row & 1;
                    us val = f2bf(v);
                    us* base = (us*)Cout;
                    if (which == 0) {
                        if (row >= 2048)
                            base[(((size_t)(bb * 16 + nn)) * 1024 + ((row - 2048) >> 1)) * 64 + dd] = val;
                    } else if (which == 1) {
                        int j = row >> 1;
                        int jt = j >> 6, ff = (j >> 4) & 3, lmw = j & 15;
                        int ks2 = dd >> 5, lg2 = (dd >> 3) & 3, e2 = dd & 7;
                        (base + 2097152)[((((size_t)(bb * 16 + nn)) * 32 + jt) * 8 + ff * 2 + ks2) * 512
                                         + (lg2 * 16 + lmw) * 8 + e2] = val;
                    } else {
                        int j = row >> 1;
                        int jt = j >> 6, ks2 = (j >> 5) & 1, lg2 = (j >> 3) & 3, e2 = j & 7;
                        int df = dd >> 4, lmw = dd & 15;
                        (base + 6291456)[((((size_t)(bb * 16 + nn)) * 32 + jt) * 8 + df * 2 + ks2) * 512
                                         + (lg2 * 16 + lmw) * 8 + e2] = val;
                    }
                }
            }
        }
    }
}

// ---------------- merged projections: qkv (192 blocks) + kr (72 blocks) -----
__global__ __launch_bounds__(512) void proj8_k(
    const us* __restrict__ cat_bf, const us* __restrict__ wqkv_t,
    const us* __restrict__ r_bf, const us* __restrict__ wr_t,
    us* __restrict__ qkv_out, us* __restrict__ krf_out)
{
    __shared__ __align__(16) us As8[2 * 2 * 8192];
    __shared__ __align__(16) us Bs8[2 * 2 * 8192];
    int bid = blockIdx.x;
    if (bid < 192) {
        int swz = (bid & 7) * 24 + (bid >> 3);
        gemm8_core<4>(cat_bf, wqkv_t, nullptr, qkv_out, 3072, 1024, 0,
                      0, true, swz % 12, swz / 12, As8, Bs8);
    } else {
        int idx = bid - 192;
        gemm8_core<3>(r_bf, wr_t, nullptr, krf_out, 1024, 1024, 0,
                      0, true, idx & 3, idx >> 2, As8, Bs8);
    }
}

// ---------------- 4-wave 2-phase GEMM core (wo / ff1 / ff2) -----------------
template<int TM, int EPI>
__device__ __forceinline__ void gemm_core(
    const us* __restrict__ A, const us* __restrict__ Bt,
    const float* __restrict__ bias, void* __restrict__ Cout,
    int N, int K, int kbeg, int kchunk, size_t zoff, bool zfirst,
    int bx, int by, us* __restrict__ As, us* __restrict__ Bs)
{
    constexpr int MF = TM / 32;
    constexpr int AISS = TM / 64;
    const int tid = threadIdx.x;
    const int w = tid >> 6, l = tid & 63;
    const int lm = l & 15, lg = l >> 4;
    const int m0 = by * TM, n0 = bx * 128;
    const int wr = (w >> 1) * (TM / 2), wc = (w & 1) * 64;
    const int nt = kchunk / 32;

    f32x4 acc[MF][4] = {};

    auto stage = [&](int buf, int k0) {
        #pragma unroll
        for (int u = 0; u < AISS; ++u) {
            int c = (u * 4 + w) * 64 + l;
            int row = c & (TM - 1), kc = c >> (TM == 128 ? 7 : 6);
            gload16(A + (size_t)(m0 + row) * K + k0 + kc * 8,
                    As + buf * (TM * 32) + (u * 4 + w) * 512);
        }
        #pragma unroll
        for (int u = 0; u < 2; ++u) {
            int c = (u * 4 + w) * 64 + l;
            int row = c & 127, kc = c >> 7;
            gload16(Bt + (size_t)(n0 + row) * K + k0 + kc * 8,
                    Bs + buf * 4096 + (u * 4 + w) * 512);
        }
    };

    stage(0, kbeg);
    int cur = 0;
    for (int t = 0; t < nt; ++t) {
        asm volatile("s_waitcnt vmcnt(0)" ::: "memory");
        __builtin_amdgcn_s_barrier();
        asm volatile("" ::: "memory");
        if (t + 1 < nt) stage(cur ^ 1, kbeg + (t + 1) * 32);

        s16x8 af[MF], bfr[4];
        #pragma unroll
        for (int mf = 0; mf < MF; ++mf)
            af[mf] = *(const s16x8*)&As[cur * (TM * 32) + (lg * TM + wr + mf * 16 + lm) * 8];
        #pragma unroll
        for (int nf = 0; nf < 4; ++nf)
            bfr[nf] = *(const s16x8*)&Bs[cur * 4096 + (lg * 128 + wc + nf * 16 + lm) * 8];
        #pragma unroll
        for (int mf = 0; mf < MF; ++mf)
            #pragma unroll
            for (int nf = 0; nf < 4; ++nf)
                acc[mf][nf] = __builtin_amdgcn_mfma_f32_16x16x32_bf16(
                    af[mf], bfr[nf], acc[mf][nf], 0, 0, 0);
        cur ^= 1;
    }

    #pragma unroll
    for (int mf = 0; mf < MF; ++mf) {
        #pragma unroll
        for (int nf = 0; nf < 4; ++nf) {
            #pragma unroll
            for (int rr = 0; rr < 4; ++rr) {
                int row = m0 + wr + mf * 16 + lg * 4 + rr;
                int col = n0 + wc + nf * 16 + lm;
                float v = acc[mf][nf][rr];
                if (EPI == 1 || (EPI == 2 && zfirst)) v += bias[col];
                if (EPI == 1) {
                    float targ = 0.7978845608028654f * (v + 0.044715f * v * v * v);
                    v = 0.5f * v * (1.0f + tanhf(targ));
                    ((us*)Cout)[(size_t)row * N + col] = f2bf(v);
                } else {
                    ((float*)Cout + zoff)[(size_t)row * N + col] = v;
                }
            }
        }
    }
}

template<int TM, int EPI>
__global__ __launch_bounds__(256) void gemm2(
    const us* __restrict__ A, const us* __restrict__ Bt,
    const float* __restrict__ bias, void* __restrict__ Cout,
    int N, int K, int kchunk, size_t zstride)
{
    __shared__ us As[2 * TM * 32];
    __shared__ us Bs[2 * 128 * 32];
    int lin = blockIdx.y * gridDim.x + blockIdx.x;
    int nwg = gridDim.x * gridDim.y;
    int swz = (lin & 7) * (nwg >> 3) + (lin >> 3);
    int bx = swz % gridDim.x, by = swz / gridDim.x;
    gemm_core<TM, EPI>(A, Bt, bias, Cout, N, K, blockIdx.z * kchunk, kchunk,
                       (size_t)blockIdx.z * zstride, blockIdx.z == 0, bx, by, As, Bs);
}

// ---------------- split-KV attention: partial (O f32, M, L exp2) ------------
// 1024 blocks: half = lin>>9, i0t = (lin>>5)&15, bn = lin&31.
// pidx = (half*16 + i0t)*32 + bn; po[pidx][64 rows][64 cols] f32; pm/pl[pidx][64].
__global__ __launch_bounds__(256) void attn11_k(
    const us* __restrict__ qb, const us* __restrict__ kfr, const us* __restrict__ vfr,
    const us* __restrict__ krf, const us* __restrict__ ksb,
    const float* __restrict__ rwb, const float* __restrict__ rrb,
    const float* __restrict__ rsb, const float* __restrict__ se,
    const float* __restrict__ seg,
    float* __restrict__ po, float* __restrict__ pm, float* __restrict__ pl)
{
    __shared__ float G_lds[4 * 80 * 20];
    __shared__ us P_lds[4 * 16 * 64];
    __shared__ us KS_lds[2048];
    __shared__ float Qx_lds[64][2];

    const int tid = threadIdx.x;
    const int w = tid >> 6, l = tid & 63;
    const int lm = l & 15, lg = l >> 4;
    int lin = blockIdx.x;
    const int half = lin >> 9;
    const int i0t = (lin >> 5) & 15;
    const int bn = lin & 31;
    const int i0 = i0t * 64;
    const int b = bn >> 4, n = bn & 15;
    const int i = i0 + w * 16 + lm;

    const float SC = 0.125f * 1.44269504088896340736f;

    const us* kbase = kfr + (size_t)bn * 131072;
    const us* vbase = vfr + (size_t)bn * 131072;
    const us* krbase = krf + (size_t)bn * 147456;

    gload16(ksb + b * KLEN + (w * 64 + l) * 8, &KS_lds[w * 512]);
    {
        const us* qrow = qb + ((size_t)bn * QLEN + i0 + l) * DH;
        s16x8 qv8[8];
        #pragma unroll
        for (int c = 0; c < 8; ++c) qv8[c] = *(const s16x8*)(qrow + c * 8);
        float e0 = 0.f, e1 = 0.f;
        #pragma unroll
        for (int c = 0; c < 8; ++c)
            #pragma unroll
            for (int e = 0; e < 8; ++e) {
                int d = c * 8 + e;
                float qv = bf2f((us)qv8[c][e]) + rsb[n * DH + d];
                e0 = fmaf(qv, se[(0 * NH + n) * DH + d], e0);
                e1 = fmaf(qv, se[(1 * NH + n) * DH + d], e1);
            }
        float qsI = seg[(size_t)(i0 + l) * 8192 + b * 2 + 1];
        float qs0 = seg[b * 2 + 1];
        float qs = (qsI != qs0) ? 1.f : 0.f;
        float ed = e1 - e0;
        if (w == 0) {
            Qx_lds[l][0] = (e0 + qs * ed) * SC;
            Qx_lds[l][1] = ed * (1.f - 2.f * qs) * SC;
        }
    }
    asm volatile("s_waitcnt vmcnt(0)" ::: "memory");
    __syncthreads();

    s16x8 qwf[2], qrf[2], qxf;
    {
        const us* qrow = qb + ((size_t)bn * QLEN + i) * DH;
        #pragma unroll
        for (int ks = 0; ks < 2; ++ks) {
            s16x8 v = *(const s16x8*)(qrow + ks * 32 + lg * 8);
            #pragma unroll
            for (int e = 0; e < 8; ++e) {
                int d = ks * 32 + lg * 8 + e;
                float f = bf2f((us)v[e]);
                qwf[ks][e] = (short)f2bf((f + rwb[n * DH + d]) * SC);
                qrf[ks][e] = (short)f2bf((f + rrb[n * DH + d]) * SC);
            }
        }
        #pragma unroll
        for (int e = 0; e < 8; ++e) qxf[e] = 0;
        if (lg == 0) {
            qxf[0] = (short)f2bf(Qx_lds[w * 16 + lm][0]);
            qxf[1] = (short)f2bf(Qx_lds[w * 16 + lm][1]);
        }
    }

    int njt = ((i0 + 63 + MLEN) >> 6) + 1;
    if (njt > 32) njt = 32;
    const int nj0 = (njt + 1) >> 1;
    const int jbeg = half ? nj0 : 0;
    const int jend = half ? njt : nj0;
    const int gq = 63 - (i0 >> 4) - w;

    f32x4 of[4] = {{0,0,0,0},{0,0,0,0},{0,0,0,0},{0,0,0,0}};
    float M = -3.0e38f, L = 0.f;
    float* gw = &G_lds[w * 1600];
    us* pw = &P_lds[w * 1024];

    for (int jt = jbeg; jt < jend; ++jt) {
        const int j0 = jt * 64;

        s16x8 kf[4][2], vf[4][2];
        #pragma unroll
        for (int f = 0; f < 4; ++f) {
            #pragma unroll
            for (int ks = 0; ks < 2; ++ks) {
                kf[f][ks] = *(const s16x8*)(kbase + (size_t)(((jt * 4 + f) * 2 + ks) * 64 + l) * 8);
                vf[f][ks] = *(const s16x8*)(vbase + (size_t)(((jt * 4 + f) * 2 + ks) * 64 + l) * 8);
            }
        }

        __builtin_amdgcn_s_setprio(1);
        #pragma unroll
        for (int pf = 0; pf < 5; ++pf) {
            int g = gq + 4 * jt + pf;
            f32x4 gacc = {0, 0, 0, 0};
            #pragma unroll
            for (int ks = 0; ks < 2; ++ks) {
                s16x8 a = *(const s16x8*)(krbase + (size_t)((g * 2 + ks) * 64 + l) * 8);
                gacc = __builtin_amdgcn_mfma_f32_16x16x32_bf16(a, qrf[ks], gacc, 0, 0, 0);
            }
            #pragma unroll
            for (int rr = 0; rr < 4; ++rr)
                gw[(pf * 16 + lg * 4 + rr) * 20 + lm] = gacc[rr];
        }
        f32x4 sf[4];
        #pragma unroll
        for (int f = 0; f < 4; ++f) {
            f32x4 cfr = {0, 0, 0, 0};
            cfr = __builtin_amdgcn_mfma_f32_16x16x32_bf16(kf[f][0], qwf[0], cfr, 0, 0, 0);
            cfr = __builtin_amdgcn_mfma_f32_16x16x32_bf16(kf[f][1], qwf[1], cfr, 0, 0, 0);
            s16x8 aext;
            #pragma unroll
            for (int e = 0; e < 8; ++e) aext[e] = 0;
            if (lg == 0) {
                aext[0] = (short)0x3F80;
                aext[1] = (short)KS_lds[j0 + f * 16 + lm];
            }
            cfr = __builtin_amdgcn_mfma_f32_16x16x32_bf16(aext, qxf, cfr, 0, 0, 0);
            sf[f] = cfr;
        }
        __builtin_amdgcn_s_setprio(0);

        float sv[16];
        #pragma unroll
        for (int f = 0; f < 4; ++f)
            #pragma unroll
            for (int rr = 0; rr < 4; ++rr) {
                int jl = f * 16 + lg * 4 + rr;
                sv[f * 4 + rr] = sf[f][rr] + gw[(jl + 15 - lm) * 20 + lm];
            }
        if (j0 + 63 > i0 + w * 16 + MLEN) {
            #pragma unroll
            for (int f = 0; f < 4; ++f)
                #pragma unroll
                for (int rr = 0; rr < 4; ++rr) {
                    int jl = f * 16 + lg * 4 + rr;
                    if (j0 + jl > i + MLEN) sv[f * 4 + rr] = -1.0e30f;
                }
        }
        float tmax = sv[0];
        #pragma unroll
        for (int u = 1; u < 16; ++u) tmax = fmaxf(tmax, sv[u]);
        tmax = fmaxf(tmax, __shfl_xor(tmax, 16));
        tmax = fmaxf(tmax, __shfl_xor(tmax, 32));
        float Mnew = fmaxf(M, tmax);
        float scale;
        asm("v_exp_f32 %0, %1" : "=v"(scale) : "v"(M - Mnew));
        float psum = 0.f;
        unsigned int pk[8];
        #pragma unroll
        for (int f = 0; f < 4; ++f) {
            #pragma unroll
            for (int rp = 0; rp < 2; ++rp) {
                float p0, p1;
                asm("v_exp_f32 %0, %1" : "=v"(p0) : "v"(sv[f * 4 + rp * 2] - Mnew));
                asm("v_exp_f32 %0, %1" : "=v"(p1) : "v"(sv[f * 4 + rp * 2 + 1] - Mnew));
                psum += p0 + p1;
                unsigned int pkv;
                asm("v_cvt_pk_bf16_f32 %0, %1, %2" : "=v"(pkv) : "v"(p0), "v"(p1));
                pk[f * 2 + rp] = pkv;
            }
        }
        psum += __shfl_xor(psum, 16);
        psum += __shfl_xor(psum, 32);
        L = L * scale + psum;
        M = Mnew;
        float rs4[4];
        #pragma unroll
        for (int rr = 0; rr < 4; ++rr)
            rs4[rr] = __shfl(scale, (l & 48) | (lg * 4 + rr));
        #pragma unroll
        for (int df = 0; df < 4; ++df)
            #pragma unroll
            for (int rr = 0; rr < 4; ++rr)
                of[df][rr] *= rs4[rr];
        #pragma unroll
        for (int f = 0; f < 4; ++f) {
            #pragma unroll
            for (int rp = 0; rp < 2; ++rp) {
                int jl2 = f * 16 + lg * 4 + rp * 2;
                *(unsigned int*)&pw[lm * 64 + (((jl2 * 2) ^ ((lm & 7) << 4)) >> 1)] = pk[f * 2 + rp];
            }
        }
        __builtin_amdgcn_s_setprio(1);
        #pragma unroll
        for (int ks = 0; ks < 2; ++ks) {
            s16x8 pa = *(const s16x8*)&pw[lm * 64 + (((ks * 64 + lg * 16) ^ ((lm & 7) << 4)) >> 1)];
            #pragma unroll
            for (int df = 0; df < 4; ++df)
                of[df] = __builtin_amdgcn_mfma_f32_16x16x32_bf16(pa, vf[df][ks], of[df], 0, 0, 0);
        }
        __builtin_amdgcn_s_setprio(0);
    }

    // epilogue: write unnormalized O (f32) + per-row M, L
    const int pidx = (half * 16 + i0t) * 32 + bn;
    float rl4[4], rm4[4];
    #pragma unroll
    for (int rr = 0; rr < 4; ++rr) {
        rl4[rr] = __shfl(L, (l & 48) | (lg * 4 + rr));
        rm4[rr] = __shfl(M, (l & 48) | (lg * 4 + rr));
    }
    #pragma unroll
    for (int df = 0; df < 4; ++df) {
        #pragma unroll
        for (int rr = 0; rr < 4; ++rr) {
            int rloc = w * 16 + lg * 4 + rr;
            po[((size_t)pidx * 64 + rloc) * 64 + df * 16 + lm] = of[df][rr];
        }
    }
    if (lm == 0) {
        #pragma unroll
        for (int rr = 0; rr < 4; ++rr) {
            int rloc = w * 16 + lg * 4 + rr;
            pm[pidx * 64 + rloc] = rm4[rr];
            pl[pidx * 64 + rloc] = rl4[rr];
        }
    }
}

// ---------------- combine two KV-halves -> av bf16 --------------------------
// grid 2048 (one av row each), 256 thr x 4 cols.
__global__ __launch_bounds__(256) void avcomb_k(
    const float* __restrict__ po, const float* __restrict__ pm,
    const float* __restrict__ pl, us* __restrict__ av)
{
    const int avrow = blockIdx.x;
    const int t = threadIdx.x;
    const int i = avrow >> 1, b = avrow & 1;
    const int i0t = i >> 6, rl = i & 63;
    const int col0 = t * 4;
    const int n = col0 >> 6, d0 = col0 & 63;
    const int bn = b * 16 + n;
    const int p0 = (0 + i0t) * 32 + bn;
    const int p1 = (16 + i0t) * 32 + bn;
    float M0 = pm[p0 * 64 + rl], M1 = pm[p1 * 64 + rl];
    float L0 = pl[p0 * 64 + rl], L1 = pl[p1 * 64 + rl];
    float Mx = fmaxf(M0, M1);
    float s0, s1;
    asm("v_exp_f32 %0, %1" : "=v"(s0) : "v"(M0 - Mx));
    asm("v_exp_f32 %0, %1" : "=v"(s1) : "v"(M1 - Mx));
    float inv = 1.0f / (L0 * s0 + L1 * s1);
    float4 o0 = *(const float4*)&po[((size_t)p0 * 64 + rl) * 64 + d0];
    float4 o1 = *(const float4*)&po[((size_t)p1 * 64 + rl) * 64 + d0];
    us o[4] = { f2bf((o0.x * s0 + o1.x * s1) * inv),
                f2bf((o0.y * s0 + o1.y * s1) * inv),
                f2bf((o0.z * s0 + o1.z * s1) * inv),
                f2bf((o0.w * s0 + o1.w * s1) * inv) };
    *(unsigned long long*)&av[(size_t)avrow * 1024 + col0] = *(const unsigned long long*)o;
}

// ---------------- residual + layer-norm (sums NSUM partials) ----------------
template<int NSUM, bool RESBF, bool OUTBF>
__global__ __launch_bounds__(256) void ln_k(
    const float* __restrict__ a, const void* __restrict__ resid,
    const float* __restrict__ g, const float* __restrict__ bb,
    void* __restrict__ out)
{
    __shared__ float xs[DM];
    __shared__ float red[5];
    const int r = blockIdx.x;
    const int t = threadIdx.x;
    float lsum = 0.f;
    #pragma unroll
    for (int u = 0; u < 4; ++u) {
        int hdx = t + 256 * u;
        float x = RESBF ? bf2f(((const us*)resid)[(size_t)r * DM + hdx])
                        : ((const float*)resid)[(size_t)r * DM + hdx];
        #pragma unroll
        for (int s = 0; s < NSUM; ++s)
            x += a[(size_t)s * 2097152 + (size_t)r * DM + hdx];
        xs[hdx] = x;
        lsum += x;
    }
    float m = block_reduce<false>(lsum, red, t) * (1.0f / DM);
    float lv = 0.f;
    #pragma unroll
    for (int u = 0; u < 4; ++u) {
        int hdx = t + 256 * u;
        float dd = xs[hdx] - m;
        lv += dd * dd;
    }
    float var = block_reduce<false>(lv, red, t) * (1.0f / DM);
    float rs = rsqrtf(var + 1e-12f);
    #pragma unroll
    for (int u = 0; u < 4; ++u) {
        int hdx = t + 256 * u;
        float y = (xs[hdx] - m) * rs * g[hdx] + bb[hdx];
        if (OUTBF) ((us*)out)[(size_t)r * DM + hdx] = f2bf(y);
        else       ((float*)out)[(size_t)r * DM + hdx] = y;
    }
}

// ---------------- launch -----------------------------------------------------
extern "C" void kernel_launch(void* const* d_in, const int* in_sizes, int n_in,
                              void* d_out, int out_size, void* d_ws, size_t ws_size,
                              hipStream_t stream) {
    const float* h         = (const float*)d_in[0];
    const float* mems      = (const float*)d_in[1];
    const float* r         = (const float*)d_in[2];
    const float* seg_mat   = (const float*)d_in[3];
    const float* wq        = (const float*)d_in[5];
    const float* wk        = (const float*)d_in[6];
    const float* wv        = (const float*)d_in[7];
    const float* wo        = (const float*)d_in[8];
    const float* wr        = (const float*)d_in[9];
    const float* rwb       = (const float*)d_in[10];
    const float* rrb       = (const float*)d_in[11];
    const float* rsb       = (const float*)d_in[12];
    const float* seg_embed = (const float*)d_in[13];
    const float* ln_g      = (const float*)d_in[14];
    const float* ln_b      = (const float*)d_in[15];
    const float* w1        = (const float*)d_in[16];
    const float* b1        = (const float*)d_in[17];
    const float* w2        = (const float*)d_in[18];
    const float* b2        = (const float*)d_in[19];
    const float* lf_g      = (const float*)d_in[20];
    const float* lf_b      = (const float*)d_in[21];
    float* out = (float*)d_out;
    char* W = (char*)d_ws;
    const size_t MB = 1ull << 20;

    us*    cat_bf = (us*)(W);                 // [0,8)
    us*    r_bf   = (us*)(W + 8  * MB);       // [8,20)  (dead after proj8)
    us*    wqkv_t = (us*)(W + 20 * MB);       // [20,26) (dead after proj8)
    us*    wr_t   = (us*)(W + 26 * MB);       // [26,28) (dead after proj8)
    us*    wo_b   = (us*)(W + 28 * MB);       // [28,30)
    us*    w1_t   = (us*)(W + 30 * MB);       // [30,38)
    us*    w2_t   = (us*)(W + 38 * MB);       // [38,46)
    us*    q_bf   = (us*)(W + 46 * MB);       // [46,50)
    us*    kfrag  = q_bf + 2097152;           // [50,58)
    us*    vfrag  = q_bf + 6291456;           // [58,66)
    us*    krf    = (us*)(W + 66 * MB);       // [66,75.4)
    us*    av_bf  = (us*)(W + 78 * MB);       // [78,82)
    us*    ks_bf  = (us*)(W + 82 * MB);       // 8 KB
    us*    oh_bf  = (us*)(W + 83 * MB);       // [83,87)
    float* po     = (float*)(W + 8 * MB);     // overlay [8,24): 16 MB partial O
    float* pm     = (float*)(W + 24 * MB);    // 256 KB
    float* pl     = (float*)(W + 24 * MB + 512 * 1024);  // 256 KB
    float* ao     = (float*)(W + 8 * MB);     // overlay [8,24) after combine
    us*    ff1_bf = (us*)(W + 46 * MB);       // overlay [46,62)
    float* ff2    = (float*)(W);              // overlay [0,32): 4 ff2 partials

    dim3 blk(256);
    dim3 blk8(512);
    prep_k<<<dim3(8720), blk, 0, stream>>>(mems, h, r, wo, wq, wk, wv, wr, w1, w2, seg_mat,
                                           cat_bf, r_bf, wo_b, wqkv_t, wr_t, w1_t, w2_t, ks_bf);
    proj8_k<<<dim3(264), blk8, 0, stream>>>(cat_bf, wqkv_t, r_bf, wr_t, q_bf, krf);
    attn11_k<<<dim3(1024), blk, 0, stream>>>(q_bf, kfrag, vfrag, krf, ks_bf,
                                             rwb, rrb, rsb, seg_embed, seg_mat, po, pm, pl);
    avcomb_k<<<dim3(2048), blk, 0, stream>>>(po, pm, pl, av_bf);
    gemm2<64, 0><<<dim3(8, 32, 2), blk, 0, stream>>>(av_bf, wo_b, nullptr, ao, 1024, 1024, 512, 2097152);
    ln_k<2, false, true><<<dim3(2048), blk, 0, stream>>>(ao, h, ln_g, ln_b, oh_bf);
    gemm2<128, 1><<<dim3(32, 16), blk, 0, stream>>>(oh_bf, w1_t, b1, ff1_bf, 4096, 1024, 1024, 0);
    gemm2<64, 2><<<dim3(8, 32, 4), blk, 0, stream>>>(ff1_bf, w2_t, b2, ff2, 1024, 4096, 1024, 2097152);
    ln_k<4, true, false><<<dim3(2048), blk, 0, stream>>>(ff2, oh_bf, lf_g, lf_b, out);
}

// Round 18
// 290.476 us; speedup vs baseline: 1.1359x; 1.0572x over previous
//
#include <hip/hip_runtime.h>
#include <hip/hip_bf16.h>

// XLNet rel-attn layer + FFN. Round 18: proj on 128x128 8-wave BK=64 tiles
// (64KB LDS -> 2 blocks/CU, 1040 blocks -> balanced grid; round-17's 260
// 1-block/CU launch serialized two scheduling rounds). Rest = round 17.
// QLEN=1024 MLEN=1024 BSZ=2 DM=1024 NH=16 DH=64 DI=4096 KLEN=2048 RLEN=3072.

#define QLEN 1024
#define MLEN 1024
#define DM 1024
#define NH 16
#define DH 64
#define DI 4096
#define KLEN 2048
#define RLEN 3072

typedef __attribute__((ext_vector_type(8))) short s16x8;
typedef __attribute__((ext_vector_type(4))) float f32x4;
typedef unsigned short us;

__device__ __forceinline__ float bf2f(us u) {
    union { unsigned int i; float f; } x; x.i = ((unsigned int)u) << 16; return x.f;
}
__device__ __forceinline__ us f2bf(float f) {
    union { float f; unsigned int i; } x; x.f = f;
    return (us)((x.i + 0x7fffu + ((x.i >> 16) & 1u)) >> 16);
}
__device__ __forceinline__ void gload16(const void* g, void* lds) {
    __builtin_amdgcn_global_load_lds(
        (const __attribute__((address_space(1))) unsigned int*)g,
        (__attribute__((address_space(3))) unsigned int*)lds, 16, 0, 0);
}

// ---------------- block reduction (wave=64, 4 waves/block) ------------------
template<bool ISMAX>
__device__ __forceinline__ float block_reduce(float v, float* red, int t) {
    #pragma unroll
    for (int off = 32; off > 0; off >>= 1) {
        float o = __shfl_down(v, off);
        v = ISMAX ? fmaxf(v, o) : (v + o);
    }
    if ((t & 63) == 0) red[t >> 6] = v;
    __syncthreads();
    if (t == 0) {
        float s = red[0];
        #pragma unroll
        for (int w = 1; w < 4; ++w) s = ISMAX ? fmaxf(s, red[w]) : (s + red[w]);
        red[4] = s;
    }
    __syncthreads();
    return red[4];
}

// ---------------- unified prep: converts + transposes + ks extraction -------
__global__ __launch_bounds__(256) void prep_k(
    const float* __restrict__ mems, const float* __restrict__ h,
    const float* __restrict__ r, const float* __restrict__ wo,
    const float* __restrict__ wq, const float* __restrict__ wk,
    const float* __restrict__ wv, const float* __restrict__ wr,
    const float* __restrict__ w1, const float* __restrict__ w2,
    const float* __restrict__ seg,
    us* __restrict__ cat_bf, us* __restrict__ r_bf, us* __restrict__ wo_b,
    us* __restrict__ wqkv_t, us* __restrict__ wr_t,
    us* __restrict__ w1_t, us* __restrict__ w2_t, us* __restrict__ ksb)
{
    __shared__ us tbuf[64][65];
    int bid = blockIdx.x;
    const int tid = threadIdx.x;
    if (bid < 5632) {
        int t = bid * 256 + tid;
        const float* src; us* dst; int off;
        if (t < 262144)       { src = mems; dst = cat_bf;           off = t; }
        else if (t < 524288)  { src = h;    dst = cat_bf + 2097152; off = t - 262144; }
        else if (t < 1310720) { src = r;    dst = r_bf;             off = t - 524288; }
        else                  { src = wo;   dst = wo_b;             off = t - 1310720; }
        const float4* p = (const float4*)src + 2 * (size_t)off;
        float4 a = p[0], b = p[1];
        us o[8] = { f2bf(a.x), f2bf(a.y), f2bf(a.z), f2bf(a.w),
                    f2bf(b.x), f2bf(b.y), f2bf(b.z), f2bf(b.w) };
        *((uint4*)dst + off) = *(const uint4*)o;
        return;
    }
    bid -= 5632;
    if (bid >= 3072) {
        int t = (bid - 3072) * 256 + tid;
        int bb = t >> 11, j = t & 2047;
        ksb[t] = f2bf(seg[(size_t)j * 4 + bb * 2 + 1]);
        return;
    }
    const float* in; us* out; int R, C, c0, r0;
    if (bid < 1024) {
        int z = bid >> 8, u = bid & 255;
        in  = (z == 0) ? wq : (z == 1) ? wk : (z == 2) ? wv : wr;
        out = (z < 3) ? (wqkv_t + (size_t)z * 1048576) : wr_t;
        R = 1024; C = 1024; c0 = (u & 15) * 64; r0 = (u >> 4) * 64;
    } else if (bid < 2048) {
        int u = bid - 1024;
        in = w1; out = w1_t; R = 1024; C = 4096;
        c0 = (u & 63) * 64; r0 = (u >> 6) * 64;
    } else {
        int u = bid - 2048;
        in = w2; out = w2_t; R = 4096; C = 1024;
        c0 = (u & 15) * 64; r0 = (u >> 4) * 64;
    }
    #pragma unroll
    for (int u = 0; u < 16; ++u) {
        int idx = tid + 256 * u;
        int rr = idx >> 6, cc = idx & 63;
        tbuf[cc][rr] = f2bf(in[(size_t)(r0 + rr) * C + c0 + cc]);
    }
    __syncthreads();
    #pragma unroll
    for (int u = 0; u < 16; ++u) {
        int idx = tid + 256 * u;
        int rr = idx >> 6, cc = idx & 63;
        out[(size_t)(c0 + rr) * R + r0 + cc] = tbuf[rr][cc];
    }
}

// ---------------- subtiled+XOR LDS offset (16x32 subtiles) ------------------
__device__ __forceinline__ int offe(int r, int c) {
    return ((r >> 4) * 2 + (c >> 5)) * 512 + (r & 15) * 32 + ((c & 31) ^ ((r & 8) ? 16 : 0));
}

// ---------------- 128x128 8-wave BK=64 GEMM core ----------------------------
// LDS: As/Bs = 2 x 8192 us (16KB each buf) -> 64KB total, 2 blocks/CU.
// Waves 2m x 4n (64x32 each, acc[4][2]); 2 phases/kt.
// EPI 3: kr fragment-major scatter; EPI 4: merged qkv scatter.
template<int EPI>
__device__ __forceinline__ void gemm8h_core(
    const us* __restrict__ A, const us* __restrict__ Bt, void* __restrict__ Cout,
    int N, int K, int bx, int by, us* __restrict__ As8, us* __restrict__ Bs8)
{
    const int tid = threadIdx.x;
    const int w = tid >> 6, l = tid & 63;
    const int lm = l & 15, lg = l >> 4;
    const int wm = w >> 2, wn = w & 3;
    const int m0 = by * 128, n0 = bx * 128;

    int srow[2], scol[2];
    #pragma unroll
    for (int u = 0; u < 2; ++u) {
        int sub = u * 8 + w;
        srow[u] = (sub >> 1) * 16 + (l >> 2);
        scol[u] = (sub & 1) * 32 + (((l & 3) * 8) ^ ((l & 32) ? 16 : 0));
    }

    auto stageHalf = [&](int kt1, bool isB, int u, int db) {
        const us* src = isB ? (Bt + (size_t)n0 * K) : (A + (size_t)m0 * K);
        us* dst = (isB ? Bs8 : As8) + db * 8192 + (u * 8 + w) * 512;
        gload16(src + (size_t)srow[u] * K + kt1 * 64 + scol[u], dst);
    };

    f32x4 acc[4][2] = {};
    const int nkt = K / 64;

    stageHalf(0, false, 0, 0); stageHalf(0, false, 1, 0);
    stageHalf(0, true, 0, 0);  stageHalf(0, true, 1, 0);

    for (int kt = 0; kt < nkt; ++kt) {
        const int d = kt & 1;
        asm volatile("s_waitcnt vmcnt(0)" ::: "memory");
        __builtin_amdgcn_s_barrier();
        asm volatile("" ::: "memory");
        const bool hn = (kt + 1 < nkt);
        const us* Ab = As8 + d * 8192;
        const us* Bb = Bs8 + d * 8192;

        // phase 0: rows wm*64 + [0,32)
        if (hn) { stageHalf(kt + 1, false, 0, d ^ 1); stageHalf(kt + 1, true, 0, d ^ 1); }
        s16x8 rB[2][2], rA[2][2];
        #pragma unroll
        for (int nf = 0; nf < 2; ++nf)
            #pragma unroll
            for (int kk = 0; kk < 2; ++kk)
                rB[nf][kk] = *(const s16x8*)&Bb[offe(wn * 32 + nf * 16 + lm, kk * 32 + lg * 8)];
        #pragma unroll
        for (int mf = 0; mf < 2; ++mf)
            #pragma unroll
            for (int kk = 0; kk < 2; ++kk)
                rA[mf][kk] = *(const s16x8*)&Ab[offe(wm * 64 + mf * 16 + lm, kk * 32 + lg * 8)];
        __builtin_amdgcn_s_setprio(1);
        #pragma unroll
        for (int mf = 0; mf < 2; ++mf)
            #pragma unroll
            for (int nf = 0; nf < 2; ++nf)
                #pragma unroll
                for (int kk = 0; kk < 2; ++kk)
                    acc[mf][nf] = __builtin_amdgcn_mfma_f32_16x16x32_bf16(
                        rA[mf][kk], rB[nf][kk], acc[mf][nf], 0, 0, 0);
        __builtin_amdgcn_s_setprio(0);

        // phase 1: rows wm*64 + [32,64)
        if (hn) { stageHalf(kt + 1, false, 1, d ^ 1); stageHalf(kt + 1, true, 1, d ^ 1); }
        #pragma unroll
        for (int mf = 0; mf < 2; ++mf)
            #pragma unroll
            for (int kk = 0; kk < 2; ++kk)
                rA[mf][kk] = *(const s16x8*)&Ab[offe(wm * 64 + (2 + mf) * 16 + lm, kk * 32 + lg * 8)];
        __builtin_amdgcn_s_setprio(1);
        #pragma unroll
        for (int mf = 0; mf < 2; ++mf)
            #pragma unroll
            for (int nf = 0; nf < 2; ++nf)
                #pragma unroll
                for (int kk = 0; kk < 2; ++kk)
                    acc[2 + mf][nf] = __builtin_amdgcn_mfma_f32_16x16x32_bf16(
                        rA[mf][kk], rB[nf][kk], acc[2 + mf][nf], 0, 0, 0);
        __builtin_amdgcn_s_setprio(0);
    }

    #pragma unroll
    for (int mf = 0; mf < 4; ++mf) {
        #pragma unroll
        for (int nf = 0; nf < 2; ++nf) {
            #pragma unroll
            for (int rr = 0; rr < 4; ++rr) {
                int row = m0 + wm * 64 + mf * 16 + lg * 4 + rr;
                int col = n0 + wn * 32 + nf * 16 + lm;
                float v = acc[mf][nf][rr];
                if (EPI == 3) {
                    int s = row >> 1, bb = row & 1, nn = col >> 6, dd = col & 63;
                    if (s >= 1) {
                        int g = (s - 1) >> 4, lmw = (s - 1) & 15;
                        int ks2 = dd >> 5, lg2 = (dd >> 3) & 3, e2 = dd & 7;
                        ((us*)Cout)[((((size_t)(bb * 16 + nn)) * 144 + g) * 2 + ks2) * 512
                                    + (lg2 * 16 + lmw) * 8 + e2] = f2bf(v);
                    }
                } else {  // EPI 4
                    int which = col >> 10;
                    int nn = (col >> 6) & 15, dd = col & 63, bb = row & 1;
                    us val = f2bf(v);
                    us* base = (us*)Cout;
                    if (which == 0) {
                        if (row >= 2048)
                            base[(((size_t)(bb * 16 + nn)) * 1024 + ((row - 2048) >> 1)) * 64 + dd] = val;
                    } else if (which == 1) {
                        int j = row >> 1;
                        int jt = j >> 6, ff = (j >> 4) & 3, lmw = j & 15;
                        int ks2 = dd >> 5, lg2 = (dd >> 3) & 3, e2 = dd & 7;
                        (base + 2097152)[((((size_t)(bb * 16 + nn)) * 32 + jt) * 8 + ff * 2 + ks2) * 512
                                         + (lg2 * 16 + lmw) * 8 + e2] = val;
                    } else {
                        int j = row >> 1;
                        int jt = j >> 6, ks2 = (j >> 5) & 1, lg2 = (j >> 3) & 3, e2 = j & 7;
                        int df = dd >> 4, lmw = dd & 15;
                        (base + 6291456)[((((size_t)(bb * 16 + nn)) * 32 + jt) * 8 + df * 2 + ks2) * 512
                                         + (lg2 * 16 + lmw) * 8 + e2] = val;
                    }
                }
            }
        }
    }
}

// ---------------- merged projections: qkv (768) + kr (272) = 1040 blocks ----
__global__ __launch_bounds__(512, 4) void proj8_k(
    const us* __restrict__ cat_bf, const us* __restrict__ wqkv_t,
    const us* __restrict__ r_bf, const us* __restrict__ wr_t,
    us* __restrict__ qkv_out, us* __restrict__ krf_out)
{
    __shared__ __align__(16) us As8[2 * 8192];
    __shared__ __align__(16) us Bs8[2 * 8192];
    int bid = blockIdx.x;
    if (bid < 768) {
        int swz = (bid & 7) * 96 + (bid >> 3);
        gemm8h_core<4>(cat_bf, wqkv_t, qkv_out, 3072, 1024,
                       swz % 24, swz / 24, As8, Bs8);
    } else {
        int idx = bid - 768;                  // 272: M=4352 (34) x N=1024 (8)
        int swz = (idx & 7) * 34 + (idx >> 3);
        gemm8h_core<3>(r_bf, wr_t, krf_out, 1024, 1024,
                       swz % 8, swz / 8, As8, Bs8);
    }
}

// ---------------- 4-wave 2-phase GEMM core (wo / ff1 / ff2) -----------------
template<int TM, int EPI>
__device__ __forceinline__ void gemm_core(
    const us* __restrict__ A, const us* __restrict__ Bt,
    const float* __restrict__ bias, void* __restrict__ Cout,
    int N, int K, int kbeg, int kchunk, size_t zoff, bool zfirst,
    int bx, int by, us* __restrict__ As, us* __restrict__ Bs)
{
    constexpr int MF = TM / 32;
    constexpr int AISS = TM / 64;
    const int tid = threadIdx.x;
    const int w = tid >> 6, l = tid & 63;
    const int lm = l & 15, lg = l >> 4;
    const int m0 = by * TM, n0 = bx * 128;
    const int wr = (w >> 1) * (TM / 2), wc = (w & 1) * 64;
    const int nt = kchunk / 32;

    f32x4 acc[MF][4] = {};

    auto stage = [&](int buf, int k0) {
        #pragma unroll
        for (int u = 0; u < AISS; ++u) {
            int c = (u * 4 + w) * 64 + l;
            int row = c & (TM - 1), kc = c >> (TM == 128 ? 7 : 6);
            gload16(A + (size_t)(m0 + row) * K + k0 + kc * 8,
                    As + buf * (TM * 32) + (u * 4 + w) * 512);
        }
        #pragma unroll
        for (int u = 0; u < 2; ++u) {
            int c = (u * 4 + w) * 64 + l;
            int row = c & 127, kc = c >> 7;
            gload16(Bt + (size_t)(n0 + row) * K + k0 + kc * 8,
                    Bs + buf * 4096 + (u * 4 + w) * 512);
        }
    };

    stage(0, kbeg);
    int cur = 0;
    for (int t = 0; t < nt; ++t) {
        asm volatile("s_waitcnt vmcnt(0)" ::: "memory");
        __builtin_amdgcn_s_barrier();
        asm volatile("" ::: "memory");
        if (t + 1 < nt) stage(cur ^ 1, kbeg + (t + 1) * 32);

        s16x8 af[MF], bfr[4];
        #pragma unroll
        for (int mf = 0; mf < MF; ++mf)
            af[mf] = *(const s16x8*)&As[cur * (TM * 32) + (lg * TM + wr + mf * 16 + lm) * 8];
        #pragma unroll
        for (int nf = 0; nf < 4; ++nf)
            bfr[nf] = *(const s16x8*)&Bs[cur * 4096 + (lg * 128 + wc + nf * 16 + lm) * 8];
        #pragma unroll
        for (int mf = 0; mf < MF; ++mf)
            #pragma unroll
            for (int nf = 0; nf < 4; ++nf)
                acc[mf][nf] = __builtin_amdgcn_mfma_f32_16x16x32_bf16(
                    af[mf], bfr[nf], acc[mf][nf], 0, 0, 0);
        cur ^= 1;
    }

    #pragma unroll
    for (int mf = 0; mf < MF; ++mf) {
        #pragma unroll
        for (int nf = 0; nf < 4; ++nf) {
            #pragma unroll
            for (int rr = 0; rr < 4; ++rr) {
                int row = m0 + wr + mf * 16 + lg * 4 + rr;
                int col = n0 + wc + nf * 16 + lm;
                float v = acc[mf][nf][rr];
                if (EPI == 1 || (EPI == 2 && zfirst)) v += bias[col];
                if (EPI == 1) {
                    float targ = 0.7978845608028654f * (v + 0.044715f * v * v * v);
                    v = 0.5f * v * (1.0f + tanhf(targ));
                    ((us*)Cout)[(size_t)row * N + col] = f2bf(v);
                } else {
                    ((float*)Cout + zoff)[(size_t)row * N + col] = v;
                }
            }
        }
    }
}

template<int TM, int EPI>
__global__ __launch_bounds__(256) void gemm2(
    const us* __restrict__ A, const us* __restrict__ Bt,
    const float* __restrict__ bias, void* __restrict__ Cout,
    int N, int K, int kchunk, size_t zstride)
{
    __shared__ us As[2 * TM * 32];
    __shared__ us Bs[2 * 128 * 32];
    int lin = blockIdx.y * gridDim.x + blockIdx.x;
    int nwg = gridDim.x * gridDim.y;
    int swz = (lin & 7) * (nwg >> 3) + (lin >> 3);
    int bx = swz % gridDim.x, by = swz / gridDim.x;
    gemm_core<TM, EPI>(A, Bt, bias, Cout, N, K, blockIdx.z * kchunk, kchunk,
                       (size_t)blockIdx.z * zstride, blockIdx.z == 0, bx, by, As, Bs);
}

// ---------------- split-KV attention: partial (O f32, M, L exp2) ------------
__global__ __launch_bounds__(256) void attn11_k(
    const us* __restrict__ qb, const us* __restrict__ kfr, const us* __restrict__ vfr,
    const us* __restrict__ krf, const us* __restrict__ ksb,
    const float* __restrict__ rwb, const float* __restrict__ rrb,
    const float* __restrict__ rsb, const float* __restrict__ se,
    const float* __restrict__ seg,
    float* __restrict__ po, float* __restrict__ pm, float* __restrict__ pl)
{
    __shared__ float G_lds[4 * 80 * 20];
    __shared__ us P_lds[4 * 16 * 64];
    __shared__ us KS_lds[2048];
    __shared__ float Qx_lds[64][2];

    const int tid = threadIdx.x;
    const int w = tid >> 6, l = tid & 63;
    const int lm = l & 15, lg = l >> 4;
    int lin = blockIdx.x;
    const int half = lin >> 9;
    const int i0t = (lin >> 5) & 15;
    const int bn = lin & 31;
    const int i0 = i0t * 64;
    const int b = bn >> 4, n = bn & 15;
    const int i = i0 + w * 16 + lm;

    const float SC = 0.125f * 1.44269504088896340736f;

    const us* kbase = kfr + (size_t)bn * 131072;
    const us* vbase = vfr + (size_t)bn * 131072;
    const us* krbase = krf + (size_t)bn * 147456;

    gload16(ksb + b * KLEN + (w * 64 + l) * 8, &KS_lds[w * 512]);
    {
        const us* qrow = qb + ((size_t)bn * QLEN + i0 + l) * DH;
        s16x8 qv8[8];
        #pragma unroll
        for (int c = 0; c < 8; ++c) qv8[c] = *(const s16x8*)(qrow + c * 8);
        float e0 = 0.f, e1 = 0.f;
        #pragma unroll
        for (int c = 0; c < 8; ++c)
            #pragma unroll
            for (int e = 0; e < 8; ++e) {
                int d = c * 8 + e;
                float qv = bf2f((us)qv8[c][e]) + rsb[n * DH + d];
                e0 = fmaf(qv, se[(0 * NH + n) * DH + d], e0);
                e1 = fmaf(qv, se[(1 * NH + n) * DH + d], e1);
            }
        float qsI = seg[(size_t)(i0 + l) * 8192 + b * 2 + 1];
        float qs0 = seg[b * 2 + 1];
        float qs = (qsI != qs0) ? 1.f : 0.f;
        float ed = e1 - e0;
        if (w == 0) {
            Qx_lds[l][0] = (e0 + qs * ed) * SC;
            Qx_lds[l][1] = ed * (1.f - 2.f * qs) * SC;
        }
    }
    asm volatile("s_waitcnt vmcnt(0)" ::: "memory");
    __syncthreads();

    s16x8 qwf[2], qrf[2], qxf;
    {
        const us* qrow = qb + ((size_t)bn * QLEN + i) * DH;
        #pragma unroll
        for (int ks = 0; ks < 2; ++ks) {
            s16x8 v = *(const s16x8*)(qrow + ks * 32 + lg * 8);
            #pragma unroll
            for (int e = 0; e < 8; ++e) {
                int d = ks * 32 + lg * 8 + e;
                float f = bf2f((us)v[e]);
                qwf[ks][e] = (short)f2bf((f + rwb[n * DH + d]) * SC);
                qrf[ks][e] = (short)f2bf((f + rrb[n * DH + d]) * SC);
            }
        }
        #pragma unroll
        for (int e = 0; e < 8; ++e) qxf[e] = 0;
        if (lg == 0) {
            qxf[0] = (short)f2bf(Qx_lds[w * 16 + lm][0]);
            qxf[1] = (short)f2bf(Qx_lds[w * 16 + lm][1]);
        }
    }

    int njt = ((i0 + 63 + MLEN) >> 6) + 1;
    if (njt > 32) njt = 32;
    const int nj0 = (njt + 1) >> 1;
    const int jbeg = half ? nj0 : 0;
    const int jend = half ? njt : nj0;
    const int gq = 63 - (i0 >> 4) - w;

    f32x4 of[4] = {{0,0,0,0},{0,0,0,0},{0,0,0,0},{0,0,0,0}};
    float M = -3.0e38f, L = 0.f;
    float* gw = &G_lds[w * 1600];
    us* pw = &P_lds[w * 1024];

    for (int jt = jbeg; jt < jend; ++jt) {
        const int j0 = jt * 64;

        s16x8 kf[4][2], vf[4][2];
        #pragma unroll
        for (int f = 0; f < 4; ++f) {
            #pragma unroll
            for (int ks = 0; ks < 2; ++ks) {
                kf[f][ks] = *(const s16x8*)(kbase + (size_t)(((jt * 4 + f) * 2 + ks) * 64 + l) * 8);
                vf[f][ks] = *(const s16x8*)(vbase + (size_t)(((jt * 4 + f) * 2 + ks) * 64 + l) * 8);
            }
        }

        __builtin_amdgcn_s_setprio(1);
        #pragma unroll
        for (int pf = 0; pf < 5; ++pf) {
            int g = gq + 4 * jt + pf;
            f32x4 gacc = {0, 0, 0, 0};
            #pragma unroll
            for (int ks = 0; ks < 2; ++ks) {
                s16x8 a = *(const s16x8*)(krbase + (size_t)((g * 2 + ks) * 64 + l) * 8);
                gacc = __builtin_amdgcn_mfma_f32_16x16x32_bf16(a, qrf[ks], gacc, 0, 0, 0);
            }
            #pragma unroll
            for (int rr = 0; rr < 4; ++rr)
                gw[(pf * 16 + lg * 4 + rr) * 20 + lm] = gacc[rr];
        }
        f32x4 sf[4];
        #pragma unroll
        for (int f = 0; f < 4; ++f) {
            f32x4 cfr = {0, 0, 0, 0};
            cfr = __builtin_amdgcn_mfma_f32_16x16x32_bf16(kf[f][0], qwf[0], cfr, 0, 0, 0);
            cfr = __builtin_amdgcn_mfma_f32_16x16x32_bf16(kf[f][1], qwf[1], cfr, 0, 0, 0);
            s16x8 aext;
            #pragma unroll
            for (int e = 0; e < 8; ++e) aext[e] = 0;
            if (lg == 0) {
                aext[0] = (short)0x3F80;
                aext[1] = (short)KS_lds[j0 + f * 16 + lm];
            }
            cfr = __builtin_amdgcn_mfma_f32_16x16x32_bf16(aext, qxf, cfr, 0, 0, 0);
            sf[f] = cfr;
        }
        __builtin_amdgcn_s_setprio(0);

        float sv[16];
        #pragma unroll
        for (int f = 0; f < 4; ++f)
            #pragma unroll
            for (int rr = 0; rr < 4; ++rr) {
                int jl = f * 16 + lg * 4 + rr;
                sv[f * 4 + rr] = sf[f][rr] + gw[(jl + 15 - lm) * 20 + lm];
            }
        if (j0 + 63 > i0 + w * 16 + MLEN) {
            #pragma unroll
            for (int f = 0; f < 4; ++f)
                #pragma unroll
                for (int rr = 0; rr < 4; ++rr) {
                    int jl = f * 16 + lg * 4 + rr;
                    if (j0 + jl > i + MLEN) sv[f * 4 + rr] = -1.0e30f;
                }
        }
        float tmax = sv[0];
        #pragma unroll
        for (int u = 1; u < 16; ++u) tmax = fmaxf(tmax, sv[u]);
        tmax = fmaxf(tmax, __shfl_xor(tmax, 16));
        tmax = fmaxf(tmax, __shfl_xor(tmax, 32));
        float Mnew = fmaxf(M, tmax);
        float scale;
        asm("v_exp_f32 %0, %1" : "=v"(scale) : "v"(M - Mnew));
        float psum = 0.f;
        unsigned int pk[8];
        #pragma unroll
        for (int f = 0; f < 4; ++f) {
            #pragma unroll
            for (int rp = 0; rp < 2; ++rp) {
                float p0, p1;
                asm("v_exp_f32 %0, %1" : "=v"(p0) : "v"(sv[f * 4 + rp * 2] - Mnew));
                asm("v_exp_f32 %0, %1" : "=v"(p1) : "v"(sv[f * 4 + rp * 2 + 1] - Mnew));
                psum += p0 + p1;
                unsigned int pkv;
                asm("v_cvt_pk_bf16_f32 %0, %1, %2" : "=v"(pkv) : "v"(p0), "v"(p1));
                pk[f * 2 + rp] = pkv;
            }
        }
        psum += __shfl_xor(psum, 16);
        psum += __shfl_xor(psum, 32);
        L = L * scale + psum;
        M = Mnew;
        float rs4[4];
        #pragma unroll
        for (int rr = 0; rr < 4; ++rr)
            rs4[rr] = __shfl(scale, (l & 48) | (lg * 4 + rr));
        #pragma unroll
        for (int df = 0; df < 4; ++df)
            #pragma unroll
            for (int rr = 0; rr < 4; ++rr)
                of[df][rr] *= rs4[rr];
        #pragma unroll
        for (int f = 0; f < 4; ++f) {
            #pragma unroll
            for (int rp = 0; rp < 2; ++rp) {
                int jl2 = f * 16 + lg * 4 + rp * 2;
                *(unsigned int*)&pw[lm * 64 + (((jl2 * 2) ^ ((lm & 7) << 4)) >> 1)] = pk[f * 2 + rp];
            }
        }
        __builtin_amdgcn_s_setprio(1);
        #pragma unroll
        for (int ks = 0; ks < 2; ++ks) {
            s16x8 pa = *(const s16x8*)&pw[lm * 64 + (((ks * 64 + lg * 16) ^ ((lm & 7) << 4)) >> 1)];
            #pragma unroll
            for (int df = 0; df < 4; ++df)
                of[df] = __builtin_amdgcn_mfma_f32_16x16x32_bf16(pa, vf[df][ks], of[df], 0, 0, 0);
        }
        __builtin_amdgcn_s_setprio(0);
    }

    const int pidx = (half * 16 + i0t) * 32 + bn;
    float rl4[4], rm4[4];
    #pragma unroll
    for (int rr = 0; rr < 4; ++rr) {
        rl4[rr] = __shfl(L, (l & 48) | (lg * 4 + rr));
        rm4[rr] = __shfl(M, (l & 48) | (lg * 4 + rr));
    }
    #pragma unroll
    for (int df = 0; df < 4; ++df) {
        #pragma unroll
        for (int rr = 0; rr < 4; ++rr) {
            int rloc = w * 16 + lg * 4 + rr;
            po[((size_t)pidx * 64 + rloc) * 64 + df * 16 + lm] = of[df][rr];
        }
    }
    if (lm == 0) {
        #pragma unroll
        for (int rr = 0; rr < 4; ++rr) {
            int rloc = w * 16 + lg * 4 + rr;
            pm[pidx * 64 + rloc] = rm4[rr];
            pl[pidx * 64 + rloc] = rl4[rr];
        }
    }
}

// ---------------- combine two KV-halves -> av bf16 --------------------------
__global__ __launch_bounds__(256) void avcomb_k(
    const float* __restrict__ po, const float* __restrict__ pm,
    const float* __restrict__ pl, us* __restrict__ av)
{
    const int avrow = blockIdx.x;
    const int t = threadIdx.x;
    const int i = avrow >> 1, b = avrow & 1;
    const int i0t = i >> 6, rl = i & 63;
    const int col0 = t * 4;
    const int n = col0 >> 6, d0 = col0 & 63;
    const int bn = b * 16 + n;
    const int p0 = (0 + i0t) * 32 + bn;
    const int p1 = (16 + i0t) * 32 + bn;
    float M0 = pm[p0 * 64 + rl], M1 = pm[p1 * 64 + rl];
    float L0 = pl[p0 * 64 + rl], L1 = pl[p1 * 64 + rl];
    float Mx = fmaxf(M0, M1);
    float s0, s1;
    asm("v_exp_f32 %0, %1" : "=v"(s0) : "v"(M0 - Mx));
    asm("v_exp_f32 %0, %1" : "=v"(s1) : "v"(M1 - Mx));
    float inv = 1.0f / (L0 * s0 + L1 * s1);
    float4 o0 = *(const float4*)&po[((size_t)p0 * 64 + rl) * 64 + d0];
    float4 o1 = *(const float4*)&po[((size_t)p1 * 64 + rl) * 64 + d0];
    us o[4] = { f2bf((o0.x * s0 + o1.x * s1) * inv),
                f2bf((o0.y * s0 + o1.y * s1) * inv),
                f2bf((o0.z * s0 + o1.z * s1) * inv),
                f2bf((o0.w * s0 + o1.w * s1) * inv) };
    *(unsigned long long*)&av[(size_t)avrow * 1024 + col0] = *(const unsigned long long*)o;
}

// ---------------- residual + layer-norm (sums NSUM partials) ----------------
template<int NSUM, bool RESBF, bool OUTBF>
__global__ __launch_bounds__(256) void ln_k(
    const float* __restrict__ a, const void* __restrict__ resid,
    const float* __restrict__ g, const float* __restrict__ bb,
    void* __restrict__ out)
{
    __shared__ float xs[DM];
    __shared__ float red[5];
    const int r = blockIdx.x;
    const int t = threadIdx.x;
    float lsum = 0.f;
    #pragma unroll
    for (int u = 0; u < 4; ++u) {
        int hdx = t + 256 * u;
        float x = RESBF ? bf2f(((const us*)resid)[(size_t)r * DM + hdx])
                        : ((const float*)resid)[(size_t)r * DM + hdx];
        #pragma unroll
        for (int s = 0; s < NSUM; ++s)
            x += a[(size_t)s * 2097152 + (size_t)r * DM + hdx];
        xs[hdx] = x;
        lsum += x;
    }
    float m = block_reduce<false>(lsum, red, t) * (1.0f / DM);
    float lv = 0.f;
    #pragma unroll
    for (int u = 0; u < 4; ++u) {
        int hdx = t + 256 * u;
        float dd = xs[hdx] - m;
        lv += dd * dd;
    }
    float var = block_reduce<false>(lv, red, t) * (1.0f / DM);
    float rs = rsqrtf(var + 1e-12f);
    #pragma unroll
    for (int u = 0; u < 4; ++u) {
        int hdx = t + 256 * u;
        float y = (xs[hdx] - m) * rs * g[hdx] + bb[hdx];
        if (OUTBF) ((us*)out)[(size_t)r * DM + hdx] = f2bf(y);
        else       ((float*)out)[(size_t)r * DM + hdx] = y;
    }
}

// ---------------- launch -----------------------------------------------------
extern "C" void kernel_launch(void* const* d_in, const int* in_sizes, int n_in,
                              void* d_out, int out_size, void* d_ws, size_t ws_size,
                              hipStream_t stream) {
    const float* h         = (const float*)d_in[0];
    const float* mems      = (const float*)d_in[1];
    const float* r         = (const float*)d_in[2];
    const float* seg_mat   = (const float*)d_in[3];
    const float* wq        = (const float*)d_in[5];
    const float* wk        = (const float*)d_in[6];
    const float* wv        = (const float*)d_in[7];
    const float* wo        = (const float*)d_in[8];
    const float* wr        = (const float*)d_in[9];
    const float* rwb       = (const float*)d_in[10];
    const float* rrb       = (const float*)d_in[11];
    const float* rsb       = (const float*)d_in[12];
    const float* seg_embed = (const float*)d_in[13];
    const float* ln_g      = (const float*)d_in[14];
    const float* ln_b      = (const float*)d_in[15];
    const float* w1        = (const float*)d_in[16];
    const float* b1        = (const float*)d_in[17];
    const float* w2        = (const float*)d_in[18];
    const float* b2        = (const float*)d_in[19];
    const float* lf_g      = (const float*)d_in[20];
    const float* lf_b      = (const float*)d_in[21];
    float* out = (float*)d_out;
    char* W = (char*)d_ws;
    const size_t MB = 1ull << 20;

    us*    cat_bf = (us*)(W);                 // [0,8)
    us*    r_bf   = (us*)(W + 8  * MB);       // [8,20)
    us*    wqkv_t = (us*)(W + 20 * MB);       // [20,26)
    us*    wr_t   = (us*)(W + 26 * MB);       // [26,28)
    us*    wo_b   = (us*)(W + 28 * MB);       // [28,30)
    us*    w1_t   = (us*)(W + 30 * MB);       // [30,38)
    us*    w2_t   = (us*)(W + 38 * MB);       // [38,46)
    us*    q_bf   = (us*)(W + 46 * MB);       // [46,50)
    us*    kfrag  = q_bf + 2097152;           // [50,58)
    us*    vfrag  = q_bf + 6291456;           // [58,66)
    us*    krf    = (us*)(W + 66 * MB);       // [66,75.4)
    us*    av_bf  = (us*)(W + 78 * MB);       // [78,82)
    us*    ks_bf  = (us*)(W + 82 * MB);       // 8 KB
    us*    oh_bf  = (us*)(W + 83 * MB);       // [83,87)
    float* po     = (float*)(W + 8 * MB);     // overlay [8,24): 16 MB partial O
    float* pm     = (float*)(W + 24 * MB);    // 256 KB
    float* pl     = (float*)(W + 24 * MB + 512 * 1024);  // 256 KB
    float* ao     = (float*)(W + 8 * MB);     // overlay [8,24) after combine
    us*    ff1_bf = (us*)(W + 46 * MB);       // overlay [46,62)
    float* ff2    = (float*)(W);              // overlay [0,32): 4 ff2 partials

    dim3 blk(256);
    dim3 blk8(512);
    prep_k<<<dim3(8720), blk, 0, stream>>>(mems, h, r, wo, wq, wk, wv, wr, w1, w2, seg_mat,
                                           cat_bf, r_bf, wo_b, wqkv_t, wr_t, w1_t, w2_t, ks_bf);
    proj8_k<<<dim3(1040), blk8, 0, stream>>>(cat_bf, wqkv_t, r_bf, wr_t, q_bf, krf);
    attn11_k<<<dim3(1024), blk, 0, stream>>>(q_bf, kfrag, vfrag, krf, ks_bf,
                                             rwb, rrb, rsb, seg_embed, seg_mat, po, pm, pl);
    avcomb_k<<<dim3(2048), blk, 0, stream>>>(po, pm, pl, av_bf);
    gemm2<64, 0><<<dim3(8, 32, 2), blk, 0, stream>>>(av_bf, wo_b, nullptr, ao, 1024, 1024, 512, 2097152);
    ln_k<2, false, true><<<dim3(2048), blk, 0, stream>>>(ao, h, ln_g, ln_b, oh_bf);
    gemm2<128, 1><<<dim3(32, 16), blk, 0, stream>>>(oh_bf, w1_t, b1, ff1_bf, 4096, 1024, 1024, 0);
    gemm2<64, 2><<<dim3(8, 32, 4), blk, 0, stream>>>(ff1_bf, w2_t, b2, ff2, 1024, 4096, 1024, 2097152);
    ln_k<4, true, false><<<dim3(2048), blk, 0, stream>>>(ff2, oh_bf, lf_g, lf_b, out);
}

// Round 19
// 246.996 us; speedup vs baseline: 1.3358x; 1.1760x over previous
//
#include <hip/hip_runtime.h>
#include <hip/hip_bf16.h>

// XLNet rel-attn layer + FFN. Round 19: ff1/ff2 moved to the 128x128 8-wave
// BK=64 core (proven by proj8 in r18): ff1 = 512 blocks EPI1 (bias+gelu),
// ff2 = 128x4 split-K EPI2. Rest identical to round 18.
// QLEN=1024 MLEN=1024 BSZ=2 DM=1024 NH=16 DH=64 DI=4096 KLEN=2048 RLEN=3072.

#define QLEN 1024
#define MLEN 1024
#define DM 1024
#define NH 16
#define DH 64
#define DI 4096
#define KLEN 2048
#define RLEN 3072

typedef __attribute__((ext_vector_type(8))) short s16x8;
typedef __attribute__((ext_vector_type(4))) float f32x4;
typedef unsigned short us;

__device__ __forceinline__ float bf2f(us u) {
    union { unsigned int i; float f; } x; x.i = ((unsigned int)u) << 16; return x.f;
}
__device__ __forceinline__ us f2bf(float f) {
    union { float f; unsigned int i; } x; x.f = f;
    return (us)((x.i + 0x7fffu + ((x.i >> 16) & 1u)) >> 16);
}
__device__ __forceinline__ void gload16(const void* g, void* lds) {
    __builtin_amdgcn_global_load_lds(
        (const __attribute__((address_space(1))) unsigned int*)g,
        (__attribute__((address_space(3))) unsigned int*)lds, 16, 0, 0);
}

// ---------------- block reduction (wave=64, 4 waves/block) ------------------
template<bool ISMAX>
__device__ __forceinline__ float block_reduce(float v, float* red, int t) {
    #pragma unroll
    for (int off = 32; off > 0; off >>= 1) {
        float o = __shfl_down(v, off);
        v = ISMAX ? fmaxf(v, o) : (v + o);
    }
    if ((t & 63) == 0) red[t >> 6] = v;
    __syncthreads();
    if (t == 0) {
        float s = red[0];
        #pragma unroll
        for (int w = 1; w < 4; ++w) s = ISMAX ? fmaxf(s, red[w]) : (s + red[w]);
        red[4] = s;
    }
    __syncthreads();
    return red[4];
}

// ---------------- unified prep: converts + transposes + ks extraction -------
__global__ __launch_bounds__(256) void prep_k(
    const float* __restrict__ mems, const float* __restrict__ h,
    const float* __restrict__ r, const float* __restrict__ wo,
    const float* __restrict__ wq, const float* __restrict__ wk,
    const float* __restrict__ wv, const float* __restrict__ wr,
    const float* __restrict__ w1, const float* __restrict__ w2,
    const float* __restrict__ seg,
    us* __restrict__ cat_bf, us* __restrict__ r_bf, us* __restrict__ wo_b,
    us* __restrict__ wqkv_t, us* __restrict__ wr_t,
    us* __restrict__ w1_t, us* __restrict__ w2_t, us* __restrict__ ksb)
{
    __shared__ us tbuf[64][65];
    int bid = blockIdx.x;
    const int tid = threadIdx.x;
    if (bid < 5632) {
        int t = bid * 256 + tid;
        const float* src; us* dst; int off;
        if (t < 262144)       { src = mems; dst = cat_bf;           off = t; }
        else if (t < 524288)  { src = h;    dst = cat_bf + 2097152; off = t - 262144; }
        else if (t < 1310720) { src = r;    dst = r_bf;             off = t - 524288; }
        else                  { src = wo;   dst = wo_b;             off = t - 1310720; }
        const float4* p = (const float4*)src + 2 * (size_t)off;
        float4 a = p[0], b = p[1];
        us o[8] = { f2bf(a.x), f2bf(a.y), f2bf(a.z), f2bf(a.w),
                    f2bf(b.x), f2bf(b.y), f2bf(b.z), f2bf(b.w) };
        *((uint4*)dst + off) = *(const uint4*)o;
        return;
    }
    bid -= 5632;
    if (bid >= 3072) {
        int t = (bid - 3072) * 256 + tid;
        int bb = t >> 11, j = t & 2047;
        ksb[t] = f2bf(seg[(size_t)j * 4 + bb * 2 + 1]);
        return;
    }
    const float* in; us* out; int R, C, c0, r0;
    if (bid < 1024) {
        int z = bid >> 8, u = bid & 255;
        in  = (z == 0) ? wq : (z == 1) ? wk : (z == 2) ? wv : wr;
        out = (z < 3) ? (wqkv_t + (size_t)z * 1048576) : wr_t;
        R = 1024; C = 1024; c0 = (u & 15) * 64; r0 = (u >> 4) * 64;
    } else if (bid < 2048) {
        int u = bid - 1024;
        in = w1; out = w1_t; R = 1024; C = 4096;
        c0 = (u & 63) * 64; r0 = (u >> 6) * 64;
    } else {
        int u = bid - 2048;
        in = w2; out = w2_t; R = 4096; C = 1024;
        c0 = (u & 15) * 64; r0 = (u >> 4) * 64;
    }
    #pragma unroll
    for (int u = 0; u < 16; ++u) {
        int idx = tid + 256 * u;
        int rr = idx >> 6, cc = idx & 63;
        tbuf[cc][rr] = f2bf(in[(size_t)(r0 + rr) * C + c0 + cc]);
    }
    __syncthreads();
    #pragma unroll
    for (int u = 0; u < 16; ++u) {
        int idx = tid + 256 * u;
        int rr = idx >> 6, cc = idx & 63;
        out[(size_t)(c0 + rr) * R + r0 + cc] = tbuf[rr][cc];
    }
}

// ---------------- subtiled+XOR LDS offset (16x32 subtiles) ------------------
__device__ __forceinline__ int offe(int r, int c) {
    return ((r >> 4) * 2 + (c >> 5)) * 512 + (r & 15) * 32 + ((c & 31) ^ ((r & 8) ? 16 : 0));
}

// ---------------- 128x128 8-wave BK=64 GEMM core ----------------------------
// EPI 1: bias+gelu->bf16; EPI 2: bias(zfirst)->f32(+zoff);
// EPI 3: kr fragment-major scatter; EPI 4: merged qkv scatter.
template<int EPI>
__device__ __forceinline__ void gemm8h_core(
    const us* __restrict__ A, const us* __restrict__ Bt,
    const float* __restrict__ bias, void* __restrict__ Cout,
    int N, int K, int kbeg, int kchunk, size_t zoff, bool zfirst,
    int bx, int by, us* __restrict__ As8, us* __restrict__ Bs8)
{
    const int tid = threadIdx.x;
    const int w = tid >> 6, l = tid & 63;
    const int lm = l & 15, lg = l >> 4;
    const int wm = w >> 2, wn = w & 3;
    const int m0 = by * 128, n0 = bx * 128;

    int srow[2], scol[2];
    #pragma unroll
    for (int u = 0; u < 2; ++u) {
        int sub = u * 8 + w;
        srow[u] = (sub >> 1) * 16 + (l >> 2);
        scol[u] = (sub & 1) * 32 + (((l & 3) * 8) ^ ((l & 32) ? 16 : 0));
    }

    auto stageHalf = [&](int kt1, bool isB, int u, int db) {
        const us* src = isB ? (Bt + (size_t)n0 * K) : (A + (size_t)m0 * K);
        us* dst = (isB ? Bs8 : As8) + db * 8192 + (u * 8 + w) * 512;
        gload16(src + (size_t)srow[u] * K + kbeg + kt1 * 64 + scol[u], dst);
    };

    f32x4 acc[4][2] = {};
    const int nkt = kchunk / 64;

    stageHalf(0, false, 0, 0); stageHalf(0, false, 1, 0);
    stageHalf(0, true, 0, 0);  stageHalf(0, true, 1, 0);

    for (int kt = 0; kt < nkt; ++kt) {
        const int d = kt & 1;
        asm volatile("s_waitcnt vmcnt(0)" ::: "memory");
        __builtin_amdgcn_s_barrier();
        asm volatile("" ::: "memory");
        const bool hn = (kt + 1 < nkt);
        const us* Ab = As8 + d * 8192;
        const us* Bb = Bs8 + d * 8192;

        // phase 0: rows wm*64 + [0,32)
        if (hn) { stageHalf(kt + 1, false, 0, d ^ 1); stageHalf(kt + 1, true, 0, d ^ 1); }
        s16x8 rB[2][2], rA[2][2];
        #pragma unroll
        for (int nf = 0; nf < 2; ++nf)
            #pragma unroll
            for (int kk = 0; kk < 2; ++kk)
                rB[nf][kk] = *(const s16x8*)&Bb[offe(wn * 32 + nf * 16 + lm, kk * 32 + lg * 8)];
        #pragma unroll
        for (int mf = 0; mf < 2; ++mf)
            #pragma unroll
            for (int kk = 0; kk < 2; ++kk)
                rA[mf][kk] = *(const s16x8*)&Ab[offe(wm * 64 + mf * 16 + lm, kk * 32 + lg * 8)];
        __builtin_amdgcn_s_setprio(1);
        #pragma unroll
        for (int mf = 0; mf < 2; ++mf)
            #pragma unroll
            for (int nf = 0; nf < 2; ++nf)
                #pragma unroll
                for (int kk = 0; kk < 2; ++kk)
                    acc[mf][nf] = __builtin_amdgcn_mfma_f32_16x16x32_bf16(
                        rA[mf][kk], rB[nf][kk], acc[mf][nf], 0, 0, 0);
        __builtin_amdgcn_s_setprio(0);

        // phase 1: rows wm*64 + [32,64)
        if (hn) { stageHalf(kt + 1, false, 1, d ^ 1); stageHalf(kt + 1, true, 1, d ^ 1); }
        #pragma unroll
        for (int mf = 0; mf < 2; ++mf)
            #pragma unroll
            for (int kk = 0; kk < 2; ++kk)
                rA[mf][kk] = *(const s16x8*)&Ab[offe(wm * 64 + (2 + mf) * 16 + lm, kk * 32 + lg * 8)];
        __builtin_amdgcn_s_setprio(1);
        #pragma unroll
        for (int mf = 0; mf < 2; ++mf)
            #pragma unroll
            for (int nf = 0; nf < 2; ++nf)
                #pragma unroll
                for (int kk = 0; kk < 2; ++kk)
                    acc[2 + mf][nf] = __builtin_amdgcn_mfma_f32_16x16x32_bf16(
                        rA[mf][kk], rB[nf][kk], acc[2 + mf][nf], 0, 0, 0);
        __builtin_amdgcn_s_setprio(0);
    }

    #pragma unroll
    for (int mf = 0; mf < 4; ++mf) {
        #pragma unroll
        for (int nf = 0; nf < 2; ++nf) {
            #pragma unroll
            for (int rr = 0; rr < 4; ++rr) {
                int row = m0 + wm * 64 + mf * 16 + lg * 4 + rr;
                int col = n0 + wn * 32 + nf * 16 + lm;
                float v = acc[mf][nf][rr];
                if (EPI == 1 || (EPI == 2 && zfirst)) v += bias[col];
                if (EPI == 1) {
                    float targ = 0.7978845608028654f * (v + 0.044715f * v * v * v);
                    v = 0.5f * v * (1.0f + tanhf(targ));
                    ((us*)Cout)[(size_t)row * N + col] = f2bf(v);
                } else if (EPI == 2) {
                    ((float*)Cout + zoff)[(size_t)row * N + col] = v;
                } else if (EPI == 3) {
                    int s = row >> 1, bb = row & 1, nn = col >> 6, dd = col & 63;
                    if (s >= 1) {
                        int g = (s - 1) >> 4, lmw = (s - 1) & 15;
                        int ks2 = dd >> 5, lg2 = (dd >> 3) & 3, e2 = dd & 7;
                        ((us*)Cout)[((((size_t)(bb * 16 + nn)) * 144 + g) * 2 + ks2) * 512
                                    + (lg2 * 16 + lmw) * 8 + e2] = f2bf(v);
                    }
                } else {  // EPI 4
                    int which = col >> 10;
                    int nn = (col >> 6) & 15, dd = col & 63, bb = row & 1;
                    us val = f2bf(v);
                    us* base = (us*)Cout;
                    if (which == 0) {
                        if (row >= 2048)
                            base[(((size_t)(bb * 16 + nn)) * 1024 + ((row - 2048) >> 1)) * 64 + dd] = val;
                    } else if (which == 1) {
                        int j = row >> 1;
                        int jt = j >> 6, ff = (j >> 4) & 3, lmw = j & 15;
                        int ks2 = dd >> 5, lg2 = (dd >> 3) & 3, e2 = dd & 7;
                        (base + 2097152)[((((size_t)(bb * 16 + nn)) * 32 + jt) * 8 + ff * 2 + ks2) * 512
                                         + (lg2 * 16 + lmw) * 8 + e2] = val;
                    } else {
                        int j = row >> 1;
                        int jt = j >> 6, ks2 = (j >> 5) & 1, lg2 = (j >> 3) & 3, e2 = j & 7;
                        int df = dd >> 4, lmw = dd & 15;
                        (base + 6291456)[((((size_t)(bb * 16 + nn)) * 32 + jt) * 8 + df * 2 + ks2) * 512
                                         + (lg2 * 16 + lmw) * 8 + e2] = val;
                    }
                }
            }
        }
    }
}

// ---------------- merged projections: qkv (768) + kr (272) = 1040 blocks ----
__global__ __launch_bounds__(512, 4) void proj8_k(
    const us* __restrict__ cat_bf, const us* __restrict__ wqkv_t,
    const us* __restrict__ r_bf, const us* __restrict__ wr_t,
    us* __restrict__ qkv_out, us* __restrict__ krf_out)
{
    __shared__ __align__(16) us As8[2 * 8192];
    __shared__ __align__(16) us Bs8[2 * 8192];
    int bid = blockIdx.x;
    if (bid < 768) {
        int swz = (bid & 7) * 96 + (bid >> 3);
        gemm8h_core<4>(cat_bf, wqkv_t, nullptr, qkv_out, 3072, 1024, 0, 1024,
                       0, true, swz % 24, swz / 24, As8, Bs8);
    } else {
        int idx = bid - 768;
        int swz = (idx & 7) * 34 + (idx >> 3);
        gemm8h_core<3>(r_bf, wr_t, nullptr, krf_out, 1024, 1024, 0, 1024,
                       0, true, swz % 8, swz / 8, As8, Bs8);
    }
}

// ---------------- standalone 8-wave 128^2 GEMM (ff1 / ff2) ------------------
template<int EPI>
__global__ __launch_bounds__(512, 4) void gemm8f_k(
    const us* __restrict__ A, const us* __restrict__ Bt,
    const float* __restrict__ bias, void* __restrict__ Cout,
    int N, int K, int kchunk, size_t zstride)
{
    __shared__ __align__(16) us As8[2 * 8192];
    __shared__ __align__(16) us Bs8[2 * 8192];
    int lin = blockIdx.y * gridDim.x + blockIdx.x;
    int nwg = gridDim.x * gridDim.y;
    int swz = (lin & 7) * (nwg >> 3) + (lin >> 3);
    int bx = swz % gridDim.x, by = swz / gridDim.x;
    gemm8h_core<EPI>(A, Bt, bias, Cout, N, K, blockIdx.z * kchunk, kchunk,
                     (size_t)blockIdx.z * zstride, blockIdx.z == 0, bx, by, As8, Bs8);
}

// ---------------- 4-wave 2-phase GEMM core (wo only) ------------------------
template<int TM, int EPI>
__device__ __forceinline__ void gemm_core(
    const us* __restrict__ A, const us* __restrict__ Bt,
    const float* __restrict__ bias, void* __restrict__ Cout,
    int N, int K, int kbeg, int kchunk, size_t zoff, bool zfirst,
    int bx, int by, us* __restrict__ As, us* __restrict__ Bs)
{
    constexpr int MF = TM / 32;
    constexpr int AISS = TM / 64;
    const int tid = threadIdx.x;
    const int w = tid >> 6, l = tid & 63;
    const int lm = l & 15, lg = l >> 4;
    const int m0 = by * TM, n0 = bx * 128;
    const int wr = (w >> 1) * (TM / 2), wc = (w & 1) * 64;
    const int nt = kchunk / 32;

    f32x4 acc[MF][4] = {};

    auto stage = [&](int buf, int k0) {
        #pragma unroll
        for (int u = 0; u < AISS; ++u) {
            int c = (u * 4 + w) * 64 + l;
            int row = c & (TM - 1), kc = c >> (TM == 128 ? 7 : 6);
            gload16(A + (size_t)(m0 + row) * K + k0 + kc * 8,
                    As + buf * (TM * 32) + (u * 4 + w) * 512);
        }
        #pragma unroll
        for (int u = 0; u < 2; ++u) {
            int c = (u * 4 + w) * 64 + l;
            int row = c & 127, kc = c >> 7;
            gload16(Bt + (size_t)(n0 + row) * K + k0 + kc * 8,
                    Bs + buf * 4096 + (u * 4 + w) * 512);
        }
    };

    stage(0, kbeg);
    int cur = 0;
    for (int t = 0; t < nt; ++t) {
        asm volatile("s_waitcnt vmcnt(0)" ::: "memory");
        __builtin_amdgcn_s_barrier();
        asm volatile("" ::: "memory");
        if (t + 1 < nt) stage(cur ^ 1, kbeg + (t + 1) * 32);

        s16x8 af[MF], bfr[4];
        #pragma unroll
        for (int mf = 0; mf < MF; ++mf)
            af[mf] = *(const s16x8*)&As[cur * (TM * 32) + (lg * TM + wr + mf * 16 + lm) * 8];
        #pragma unroll
        for (int nf = 0; nf < 4; ++nf)
            bfr[nf] = *(const s16x8*)&Bs[cur * 4096 + (lg * 128 + wc + nf * 16 + lm) * 8];
        #pragma unroll
        for (int mf = 0; mf < MF; ++mf)
            #pragma unroll
            for (int nf = 0; nf < 4; ++nf)
                acc[mf][nf] = __builtin_amdgcn_mfma_f32_16x16x32_bf16(
                    af[mf], bfr[nf], acc[mf][nf], 0, 0, 0);
        cur ^= 1;
    }

    #pragma unroll
    for (int mf = 0; mf < MF; ++mf) {
        #pragma unroll
        for (int nf = 0; nf < 4; ++nf) {
            #pragma unroll
            for (int rr = 0; rr < 4; ++rr) {
                int row = m0 + wr + mf * 16 + lg * 4 + rr;
                int col = n0 + wc + nf * 16 + lm;
                float v = acc[mf][nf][rr];
                if (EPI == 2 && zfirst) v += bias[col];
                ((float*)Cout + zoff)[(size_t)row * N + col] = v;
            }
        }
    }
}

template<int TM, int EPI>
__global__ __launch_bounds__(256) void gemm2(
    const us* __restrict__ A, const us* __restrict__ Bt,
    const float* __restrict__ bias, void* __restrict__ Cout,
    int N, int K, int kchunk, size_t zstride)
{
    __shared__ us As[2 * TM * 32];
    __shared__ us Bs[2 * 128 * 32];
    int lin = blockIdx.y * gridDim.x + blockIdx.x;
    int nwg = gridDim.x * gridDim.y;
    int swz = (lin & 7) * (nwg >> 3) + (lin >> 3);
    int bx = swz % gridDim.x, by = swz / gridDim.x;
    gemm_core<TM, EPI>(A, Bt, bias, Cout, N, K, blockIdx.z * kchunk, kchunk,
                       (size_t)blockIdx.z * zstride, blockIdx.z == 0, bx, by, As, Bs);
}

// ---------------- split-KV attention: partial (O f32, M, L exp2) ------------
__global__ __launch_bounds__(256) void attn11_k(
    const us* __restrict__ qb, const us* __restrict__ kfr, const us* __restrict__ vfr,
    const us* __restrict__ krf, const us* __restrict__ ksb,
    const float* __restrict__ rwb, const float* __restrict__ rrb,
    const float* __restrict__ rsb, const float* __restrict__ se,
    const float* __restrict__ seg,
    float* __restrict__ po, float* __restrict__ pm, float* __restrict__ pl)
{
    __shared__ float G_lds[4 * 80 * 20];
    __shared__ us P_lds[4 * 16 * 64];
    __shared__ us KS_lds[2048];
    __shared__ float Qx_lds[64][2];

    const int tid = threadIdx.x;
    const int w = tid >> 6, l = tid & 63;
    const int lm = l & 15, lg = l >> 4;
    int lin = blockIdx.x;
    const int half = lin >> 9;
    const int i0t = (lin >> 5) & 15;
    const int bn = lin & 31;
    const int i0 = i0t * 64;
    const int b = bn >> 4, n = bn & 15;
    const int i = i0 + w * 16 + lm;

    const float SC = 0.125f * 1.44269504088896340736f;

    const us* kbase = kfr + (size_t)bn * 131072;
    const us* vbase = vfr + (size_t)bn * 131072;
    const us* krbase = krf + (size_t)bn * 147456;

    gload16(ksb + b * KLEN + (w * 64 + l) * 8, &KS_lds[w * 512]);
    {
        const us* qrow = qb + ((size_t)bn * QLEN + i0 + l) * DH;
        s16x8 qv8[8];
        #pragma unroll
        for (int c = 0; c < 8; ++c) qv8[c] = *(const s16x8*)(qrow + c * 8);
        float e0 = 0.f, e1 = 0.f;
        #pragma unroll
        for (int c = 0; c < 8; ++c)
            #pragma unroll
            for (int e = 0; e < 8; ++e) {
                int d = c * 8 + e;
                float qv = bf2f((us)qv8[c][e]) + rsb[n * DH + d];
                e0 = fmaf(qv, se[(0 * NH + n) * DH + d], e0);
                e1 = fmaf(qv, se[(1 * NH + n) * DH + d], e1);
            }
        float qsI = seg[(size_t)(i0 + l) * 8192 + b * 2 + 1];
        float qs0 = seg[b * 2 + 1];
        float qs = (qsI != qs0) ? 1.f : 0.f;
        float ed = e1 - e0;
        if (w == 0) {
            Qx_lds[l][0] = (e0 + qs * ed) * SC;
            Qx_lds[l][1] = ed * (1.f - 2.f * qs) * SC;
        }
    }
    asm volatile("s_waitcnt vmcnt(0)" ::: "memory");
    __syncthreads();

    s16x8 qwf[2], qrf[2], qxf;
    {
        const us* qrow = qb + ((size_t)bn * QLEN + i) * DH;
        #pragma unroll
        for (int ks = 0; ks < 2; ++ks) {
            s16x8 v = *(const s16x8*)(qrow + ks * 32 + lg * 8);
            #pragma unroll
            for (int e = 0; e < 8; ++e) {
                int d = ks * 32 + lg * 8 + e;
                float f = bf2f((us)v[e]);
                qwf[ks][e] = (short)f2bf((f + rwb[n * DH + d]) * SC);
                qrf[ks][e] = (short)f2bf((f + rrb[n * DH + d]) * SC);
            }
        }
        #pragma unroll
        for (int e = 0; e < 8; ++e) qxf[e] = 0;
        if (lg == 0) {
            qxf[0] = (short)f2bf(Qx_lds[w * 16 + lm][0]);
            qxf[1] = (short)f2bf(Qx_lds[w * 16 + lm][1]);
        }
    }

    int njt = ((i0 + 63 + MLEN) >> 6) + 1;
    if (njt > 32) njt = 32;
    const int nj0 = (njt + 1) >> 1;
    const int jbeg = half ? nj0 : 0;
    const int jend = half ? njt : nj0;
    const int gq = 63 - (i0 >> 4) - w;

    f32x4 of[4] = {{0,0,0,0},{0,0,0,0},{0,0,0,0},{0,0,0,0}};
    float M = -3.0e38f, L = 0.f;
    float* gw = &G_lds[w * 1600];
    us* pw = &P_lds[w * 1024];

    for (int jt = jbeg; jt < jend; ++jt) {
        const int j0 = jt * 64;

        s16x8 kf[4][2], vf[4][2];
        #pragma unroll
        for (int f = 0; f < 4; ++f) {
            #pragma unroll
            for (int ks = 0; ks < 2; ++ks) {
                kf[f][ks] = *(const s16x8*)(kbase + (size_t)(((jt * 4 + f) * 2 + ks) * 64 + l) * 8);
                vf[f][ks] = *(const s16x8*)(vbase + (size_t)(((jt * 4 + f) * 2 + ks) * 64 + l) * 8);
            }
        }

        __builtin_amdgcn_s_setprio(1);
        #pragma unroll
        for (int pf = 0; pf < 5; ++pf) {
            int g = gq + 4 * jt + pf;
            f32x4 gacc = {0, 0, 0, 0};
            #pragma unroll
            for (int ks = 0; ks < 2; ++ks) {
                s16x8 a = *(const s16x8*)(krbase + (size_t)((g * 2 + ks) * 64 + l) * 8);
                gacc = __builtin_amdgcn_mfma_f32_16x16x32_bf16(a, qrf[ks], gacc, 0, 0, 0);
            }
            #pragma unroll
            for (int rr = 0; rr < 4; ++rr)
                gw[(pf * 16 + lg * 4 + rr) * 20 + lm] = gacc[rr];
        }
        f32x4 sf[4];
        #pragma unroll
        for (int f = 0; f < 4; ++f) {
            f32x4 cfr = {0, 0, 0, 0};
            cfr = __builtin_amdgcn_mfma_f32_16x16x32_bf16(kf[f][0], qwf[0], cfr, 0, 0, 0);
            cfr = __builtin_amdgcn_mfma_f32_16x16x32_bf16(kf[f][1], qwf[1], cfr, 0, 0, 0);
            s16x8 aext;
            #pragma unroll
            for (int e = 0; e < 8; ++e) aext[e] = 0;
            if (lg == 0) {
                aext[0] = (short)0x3F80;
                aext[1] = (short)KS_lds[j0 + f * 16 + lm];
            }
            cfr = __builtin_amdgcn_mfma_f32_16x16x32_bf16(aext, qxf, cfr, 0, 0, 0);
            sf[f] = cfr;
        }
        __builtin_amdgcn_s_setprio(0);

        float sv[16];
        #pragma unroll
        for (int f = 0; f < 4; ++f)
            #pragma unroll
            for (int rr = 0; rr < 4; ++rr) {
                int jl = f * 16 + lg * 4 + rr;
                sv[f * 4 + rr] = sf[f][rr] + gw[(jl + 15 - lm) * 20 + lm];
            }
        if (j0 + 63 > i0 + w * 16 + MLEN) {
            #pragma unroll
            for (int f = 0; f < 4; ++f)
                #pragma unroll
                for (int rr = 0; rr < 4; ++rr) {
                    int jl = f * 16 + lg * 4 + rr;
                    if (j0 + jl > i + MLEN) sv[f * 4 + rr] = -1.0e30f;
                }
        }
        float tmax = sv[0];
        #pragma unroll
        for (int u = 1; u < 16; ++u) tmax = fmaxf(tmax, sv[u]);
        tmax = fmaxf(tmax, __shfl_xor(tmax, 16));
        tmax = fmaxf(tmax, __shfl_xor(tmax, 32));
        float Mnew = fmaxf(M, tmax);
        float scale;
        asm("v_exp_f32 %0, %1" : "=v"(scale) : "v"(M - Mnew));
        float psum = 0.f;
        unsigned int pk[8];
        #pragma unroll
        for (int f = 0; f < 4; ++f) {
            #pragma unroll
            for (int rp = 0; rp < 2; ++rp) {
                float p0, p1;
                asm("v_exp_f32 %0, %1" : "=v"(p0) : "v"(sv[f * 4 + rp * 2] - Mnew));
                asm("v_exp_f32 %0, %1" : "=v"(p1) : "v"(sv[f * 4 + rp * 2 + 1] - Mnew));
                psum += p0 + p1;
                unsigned int pkv;
                asm("v_cvt_pk_bf16_f32 %0, %1, %2" : "=v"(pkv) : "v"(p0), "v"(p1));
                pk[f * 2 + rp] = pkv;
            }
        }
        psum += __shfl_xor(psum, 16);
        psum += __shfl_xor(psum, 32);
        L = L * scale + psum;
        M = Mnew;
        float rs4[4];
        #pragma unroll
        for (int rr = 0; rr < 4; ++rr)
            rs4[rr] = __shfl(scale, (l & 48) | (lg * 4 + rr));
        #pragma unroll
        for (int df = 0; df < 4; ++df)
            #pragma unroll
            for (int rr = 0; rr < 4; ++rr)
                of[df][rr] *= rs4[rr];
        #pragma unroll
        for (int f = 0; f < 4; ++f) {
            #pragma unroll
            for (int rp = 0; rp < 2; ++rp) {
                int jl2 = f * 16 + lg * 4 + rp * 2;
                *(unsigned int*)&pw[lm * 64 + (((jl2 * 2) ^ ((lm & 7) << 4)) >> 1)] = pk[f * 2 + rp];
            }
        }
        __builtin_amdgcn_s_setprio(1);
        #pragma unroll
        for (int ks = 0; ks < 2; ++ks) {
            s16x8 pa = *(const s16x8*)&pw[lm * 64 + (((ks * 64 + lg * 16) ^ ((lm & 7) << 4)) >> 1)];
            #pragma unroll
            for (int df = 0; df < 4; ++df)
                of[df] = __builtin_amdgcn_mfma_f32_16x16x32_bf16(pa, vf[df][ks], of[df], 0, 0, 0);
        }
        __builtin_amdgcn_s_setprio(0);
    }

    const int pidx = (half * 16 + i0t) * 32 + bn;
    float rl4[4], rm4[4];
    #pragma unroll
    for (int rr = 0; rr < 4; ++rr) {
        rl4[rr] = __shfl(L, (l & 48) | (lg * 4 + rr));
        rm4[rr] = __shfl(M, (l & 48) | (lg * 4 + rr));
    }
    #pragma unroll
    for (int df = 0; df < 4; ++df) {
        #pragma unroll
        for (int rr = 0; rr < 4; ++rr) {
            int rloc = w * 16 + lg * 4 + rr;
            po[((size_t)pidx * 64 + rloc) * 64 + df * 16 + lm] = of[df][rr];
        }
    }
    if (lm == 0) {
        #pragma unroll
        for (int rr = 0; rr < 4; ++rr) {
            int rloc = w * 16 + lg * 4 + rr;
            pm[pidx * 64 + rloc] = rm4[rr];
            pl[pidx * 64 + rloc] = rl4[rr];
        }
    }
}

// ---------------- combine two KV-halves -> av bf16 --------------------------
__global__ __launch_bounds__(256) void avcomb_k(
    const float* __restrict__ po, const float* __restrict__ pm,
    const float* __restrict__ pl, us* __restrict__ av)
{
    const int avrow = blockIdx.x;
    const int t = threadIdx.x;
    const int i = avrow >> 1, b = avrow & 1;
    const int i0t = i >> 6, rl = i & 63;
    const int col0 = t * 4;
    const int n = col0 >> 6, d0 = col0 & 63;
    const int bn = b * 16 + n;
    const int p0 = (0 + i0t) * 32 + bn;
    const int p1 = (16 + i0t) * 32 + bn;
    float M0 = pm[p0 * 64 + rl], M1 = pm[p1 * 64 + rl];
    float L0 = pl[p0 * 64 + rl], L1 = pl[p1 * 64 + rl];
    float Mx = fmaxf(M0, M1);
    float s0, s1;
    asm("v_exp_f32 %0, %1" : "=v"(s0) : "v"(M0 - Mx));
    asm("v_exp_f32 %0, %1" : "=v"(s1) : "v"(M1 - Mx));
    float inv = 1.0f / (L0 * s0 + L1 * s1);
    float4 o0 = *(const float4*)&po[((size_t)p0 * 64 + rl) * 64 + d0];
    float4 o1 = *(const float4*)&po[((size_t)p1 * 64 + rl) * 64 + d0];
    us o[4] = { f2bf((o0.x * s0 + o1.x * s1) * inv),
                f2bf((o0.y * s0 + o1.y * s1) * inv),
                f2bf((o0.z * s0 + o1.z * s1) * inv),
                f2bf((o0.w * s0 + o1.w * s1) * inv) };
    *(unsigned long long*)&av[(size_t)avrow * 1024 + col0] = *(const unsigned long long*)o;
}

// ---------------- residual + layer-norm (sums NSUM partials) ----------------
template<int NSUM, bool RESBF, bool OUTBF>
__global__ __launch_bounds__(256) void ln_k(
    const float* __restrict__ a, const void* __restrict__ resid,
    const float* __restrict__ g, const float* __restrict__ bb,
    void* __restrict__ out)
{
    __shared__ float xs[DM];
    __shared__ float red[5];
    const int r = blockIdx.x;
    const int t = threadIdx.x;
    float lsum = 0.f;
    #pragma unroll
    for (int u = 0; u < 4; ++u) {
        int hdx = t + 256 * u;
        float x = RESBF ? bf2f(((const us*)resid)[(size_t)r * DM + hdx])
                        : ((const float*)resid)[(size_t)r * DM + hdx];
        #pragma unroll
        for (int s = 0; s < NSUM; ++s)
            x += a[(size_t)s * 2097152 + (size_t)r * DM + hdx];
        xs[hdx] = x;
        lsum += x;
    }
    float m = block_reduce<false>(lsum, red, t) * (1.0f / DM);
    float lv = 0.f;
    #pragma unroll
    for (int u = 0; u < 4; ++u) {
        int hdx = t + 256 * u;
        float dd = xs[hdx] - m;
        lv += dd * dd;
    }
    float var = block_reduce<false>(lv, red, t) * (1.0f / DM);
    float rs = rsqrtf(var + 1e-12f);
    #pragma unroll
    for (int u = 0; u < 4; ++u) {
        int hdx = t + 256 * u;
        float y = (xs[hdx] - m) * rs * g[hdx] + bb[hdx];
        if (OUTBF) ((us*)out)[(size_t)r * DM + hdx] = f2bf(y);
        else       ((float*)out)[(size_t)r * DM + hdx] = y;
    }
}

// ---------------- launch -----------------------------------------------------
extern "C" void kernel_launch(void* const* d_in, const int* in_sizes, int n_in,
                              void* d_out, int out_size, void* d_ws, size_t ws_size,
                              hipStream_t stream) {
    const float* h         = (const float*)d_in[0];
    const float* mems      = (const float*)d_in[1];
    const float* r         = (const float*)d_in[2];
    const float* seg_mat   = (const float*)d_in[3];
    const float* wq        = (const float*)d_in[5];
    const float* wk        = (const float*)d_in[6];
    const float* wv        = (const float*)d_in[7];
    const float* wo        = (const float*)d_in[8];
    const float* wr        = (const float*)d_in[9];
    const float* rwb       = (const float*)d_in[10];
    const float* rrb       = (const float*)d_in[11];
    const float* rsb       = (const float*)d_in[12];
    const float* seg_embed = (const float*)d_in[13];
    const float* ln_g      = (const float*)d_in[14];
    const float* ln_b      = (const float*)d_in[15];
    const float* w1        = (const float*)d_in[16];
    const float* b1        = (const float*)d_in[17];
    const float* w2        = (const float*)d_in[18];
    const float* b2        = (const float*)d_in[19];
    const float* lf_g      = (const float*)d_in[20];
    const float* lf_b      = (const float*)d_in[21];
    float* out = (float*)d_out;
    char* W = (char*)d_ws;
    const size_t MB = 1ull << 20;

    us*    cat_bf = (us*)(W);                 // [0,8)
    us*    r_bf   = (us*)(W + 8  * MB);       // [8,20)
    us*    wqkv_t = (us*)(W + 20 * MB);       // [20,26)
    us*    wr_t   = (us*)(W + 26 * MB);       // [26,28)
    us*    wo_b   = (us*)(W + 28 * MB);       // [28,30)
    us*    w1_t   = (us*)(W + 30 * MB);       // [30,38)
    us*    w2_t   = (us*)(W + 38 * MB);       // [38,46)
    us*    q_bf   = (us*)(W + 46 * MB);       // [46,50)
    us*    kfrag  = q_bf + 2097152;           // [50,58)
    us*    vfrag  = q_bf + 6291456;           // [58,66)
    us*    krf    = (us*)(W + 66 * MB);       // [66,75.4)
    us*    av_bf  = (us*)(W + 78 * MB);       // [78,82)
    us*    ks_bf  = (us*)(W + 82 * MB);       // 8 KB
    us*    oh_bf  = (us*)(W + 83 * MB);       // [83,87)
    float* po     = (float*)(W + 8 * MB);     // overlay [8,24): 16 MB partial O
    float* pm     = (float*)(W + 24 * MB);    // 256 KB
    float* pl     = (float*)(W + 24 * MB + 512 * 1024);  // 256 KB
    float* ao     = (float*)(W + 8 * MB);     // overlay [8,24) after combine
    us*    ff1_bf = (us*)(W + 46 * MB);       // overlay [46,62)
    float* ff2    = (float*)(W);              // overlay [0,32): 4 ff2 partials

    dim3 blk(256);
    dim3 blk8(512);
    prep_k<<<dim3(8720), blk, 0, stream>>>(mems, h, r, wo, wq, wk, wv, wr, w1, w2, seg_mat,
                                           cat_bf, r_bf, wo_b, wqkv_t, wr_t, w1_t, w2_t, ks_bf);
    proj8_k<<<dim3(1040), blk8, 0, stream>>>(cat_bf, wqkv_t, r_bf, wr_t, q_bf, krf);
    attn11_k<<<dim3(1024), blk, 0, stream>>>(q_bf, kfrag, vfrag, krf, ks_bf,
                                             rwb, rrb, rsb, seg_embed, seg_mat, po, pm, pl);
    avcomb_k<<<dim3(2048), blk, 0, stream>>>(po, pm, pl, av_bf);
    gemm2<64, 0><<<dim3(8, 32, 2), blk, 0, stream>>>(av_bf, wo_b, nullptr, ao, 1024, 1024, 512, 2097152);
    ln_k<2, false, true><<<dim3(2048), blk, 0, stream>>>(ao, h, ln_g, ln_b, oh_bf);
    gemm8f_k<1><<<dim3(32, 16), blk8, 0, stream>>>(oh_bf, w1_t, b1, ff1_bf, 4096, 1024, 1024, 0);
    gemm8f_k<2><<<dim3(8, 16, 4), blk8, 0, stream>>>(ff1_bf, w2_t, b2, ff2, 1024, 4096, 1024, 2097152);
    ln_k<4, true, false><<<dim3(2048), blk, 0, stream>>>(ff2, oh_bf, lf_g, lf_b, out);
}